// Round 12
// baseline (4780.987 us; speedup 1.0000x reference)
//
#include <hip/hip_runtime.h>
#include <cmath>

#define DM 512
#define DH 64

typedef __attribute__((ext_vector_type(8))) short short8;
typedef __attribute__((ext_vector_type(4))) float float4v;

__device__ inline float b2f(unsigned short u){
  union{unsigned int i; float f;} z; z.i = ((unsigned)u)<<16; return z.f;
}
__device__ inline unsigned short f2b(float f){
  unsigned int x = __float_as_uint(f);
  return (unsigned short)((x + 0x7fffu + ((x>>16)&1u)) >> 16);   // RNE
}
// HW packed RNE convert: lo16 = bf16(a), hi16 = bf16(b)
__device__ inline unsigned cvtpk2(float a, float b){
  unsigned r; asm("v_cvt_pk_bf16_f32 %0, %1, %2" : "=v"(r) : "v"(a), "v"(b)); return r;
}

#define GLL(gp, lp) __builtin_amdgcn_global_load_lds((const __attribute__((address_space(1))) void*)(gp), \
    (__attribute__((address_space(3))) void*)(lp), 16, 0, 0)

// ---------------- Threefry-2x32-20 (matches jax.random) ----------------
__host__ __device__ inline void tf2x32(unsigned k0, unsigned k1, unsigned& x0, unsigned& x1){
  const unsigned ks0=k0, ks1=k1, ks2=k0^k1^0x1BD11BDAu;
  x0 += ks0; x1 += ks1;
#define TF_ROT(r) { x0 += x1; x1 = (x1<<(r))|(x1>>(32-(r))); x1 ^= x0; }
  TF_ROT(13) TF_ROT(15) TF_ROT(26) TF_ROT(6)
  x0 += ks1; x1 += ks2 + 1u;
  TF_ROT(17) TF_ROT(29) TF_ROT(16) TF_ROT(24)
  x0 += ks2; x1 += ks0 + 2u;
  TF_ROT(13) TF_ROT(15) TF_ROT(26) TF_ROT(6)
  x0 += ks0; x1 += ks1 + 3u;
  TF_ROT(17) TF_ROT(29) TF_ROT(16) TF_ROT(24)
  x0 += ks1; x1 += ks2 + 4u;
  TF_ROT(13) TF_ROT(15) TF_ROT(26) TF_ROT(6)
  x0 += ks2; x1 += ks0 + 5u;
#undef TF_ROT
}

__global__ __launch_bounds__(256) void idx_kernel(int* __restrict__ idx, unsigned k2a, unsigned k2b,
                                                  int S2, int Lmask){
  int j = blockIdx.x*256 + threadIdx.x;
  if (j >= S2) return;
  unsigned x0 = (unsigned)j, x1 = (unsigned)(S2 + j);
  tf2x32(k2a, k2b, x0, x1);
  idx[j]      = (int)(x0 & (unsigned)Lmask);
  idx[S2 + j] = (int)(x1 & (unsigned)Lmask);
}

// ---------------- positional-embedding table (batch-independent) ----------------
__global__ __launch_bounds__(256) void pe_kernel(float* __restrict__ pe, int L){
  int i = blockIdx.x*256 + threadIdx.x;
  int d = i % DM, l = i / DM;
  const float scale = -0.017988946f;  // -ln(10000)/512
  float freq = expf((float)(d & ~1) * scale);
  float ang  = (float)l * freq;
  pe[i] = (d & 1) ? cosf(ang) : sinf(ang);
}

// ---------------- transpose token-conv weights: tcwT[j][d] = tcw[d][c][kk], j=kk*7+c ----------------
__global__ __launch_bounds__(256) void packtcw(const float* __restrict__ tcw, float* __restrict__ tcwT){
  int i = blockIdx.x*256 + threadIdx.x;
  if (i >= 21*DM) return;
  int j = i / DM, d = i % DM;
  tcwT[(size_t)j*DM + d] = tcw[(size_t)d*21 + (j%7)*3 + (j/7)];
}

// ---------------- token embed: one block per (b,l) row; optional bf16 shadow hb ----------------
__global__ __launch_bounds__(256) void embed2(const float* __restrict__ x, const float* __restrict__ tcwT,
                                              const float* __restrict__ pe, float* __restrict__ h,
                                              unsigned short* __restrict__ hb, int L){
  int row = blockIdx.x; int l = row % L, b = row / L;
  __shared__ float xs[21];
  int t = threadIdx.x;
  if (t < 21){
    int c = t % 7, kk = t / 7;
    int ls = l + kk - 1; ls = (ls < 0) ? ls + L : (ls >= L ? ls - L : ls);
    xs[t] = x[((size_t)b*L + ls)*7 + c];
  }
  __syncthreads();
  for (int d = t; d < DM; d += 256){
    float acc = 0.f;
#pragma unroll
    for (int j=0;j<21;j++) acc += xs[j]*tcwT[j*DM + d];
    float val = acc + pe[(size_t)l*DM + d];
    h[(size_t)row*DM + d] = val;
    if (hb) hb[(size_t)row*DM + d] = f2b(val);
  }
}

// ---------------- fp32 -> bf16 conversion ----------------
__global__ __launch_bounds__(256) void f2b_vec(const float* __restrict__ src, unsigned short* __restrict__ dst, int n4){
  int i = blockIdx.x*256 + threadIdx.x;
  if (i >= n4) return;
  float4 v = ((const float4*)src)[i];
  uint2 o; o.x = cvtpk2(v.x, v.y); o.y = cvtpk2(v.z, v.w);
  ((uint2*)dst)[i] = o;
}

// ---------------- pack conv weights along K: wtapK[n][tap*512+c] = dcw[n][c][tap] ----------------
__global__ __launch_bounds__(256) void packconv(const float* __restrict__ dcw, unsigned short* __restrict__ wtapK){
  int i = blockIdx.x*256 + threadIdx.x;
  if (i >= 3*DM*DM) return;
  int n = i / (3*DM); int rem = i % (3*DM); int tap = rem / DM; int c = rem % DM;
  wtapK[(size_t)n*(3*DM) + tap*DM + c] = f2b(dcw[((size_t)n*DM + c)*3 + tap]);
}

// ---------------- concat qkv bias ----------------
__global__ __launch_bounds__(256) void catb_kernel(const float* __restrict__ a, const float* __restrict__ b,
    const float* __restrict__ c, float* __restrict__ o){
  int i = blockIdx.x*256 + threadIdx.x;
  if (i >= 1536) return;
  o[i] = (i < 512) ? a[i] : (i < 1024 ? b[i-512] : c[i-1024]);
}

// =======================================================================
// bgemm_dp: counted-vmcnt 3-deep pipelined GEMM (T3+T4), bf16 A, TN=64,
// K = NITER*64. LDS ring: 3 stages x (16KB A + 8KB B) = 72KB -> 2 blk/CU.
// Per iter: s_waitcnt vmcnt(12/6/0) -> barrier -> MFMA on slot t%3 ->
// barrier -> issue tile t+3 into slot t%3 (steady state never drains).
// Epilogue: conflict-free LDS-staged coalesced writeback.
// Used for QKV (bf16 shadow A) and w2 (bf16 mid A).
// =======================================================================
template<int NITER>
__global__ __launch_bounds__(256) void bgemm_dp(const unsigned short* __restrict__ A16,
    const unsigned short* __restrict__ Wb, const float* __restrict__ bias, void* __restrict__ C,
    int N, int act, int outbf, int qkv, size_t bufstride, int swz){
  constexpr int TN = 64, NJ = 2, SWM = TN/16 - 1;
  const int K = NITER*64;
  __shared__ unsigned short LDSB[3*12288];    // 3 x 24KB
  int tid = threadIdx.x;
  int w = tid >> 6, ln = tid & 63;

  int bx = blockIdx.x, by = blockIdx.y;
  if (swz){
    int XT = gridDim.x, YT = gridDim.y;
    int lid = by*XT + bx;
    int xcd = lid & 7, s = lid >> 3;
    int ych = YT >> 3;
    int CHv = ych < swz ? ych : swz;
    int yloc = s % CHv;
    int t2 = s / CHv;
    int xx = t2 % XT;
    int chunk = t2 / XT;
    by = xcd*ych + chunk*CHv + yloc;
    bx = xx;
  }
  int row0 = by*128, col0 = bx*TN;

  long aBase[4]; int aCol[4];
#pragma unroll
  for (int g=0; g<4; g++){
    int ch = g*256 + tid;
    int r = ch >> 3, c = ch & 7;
    aCol[g] = (c ^ (r & 7))*8;
    aBase[g] = (long)(row0 + r) * K;
  }
  long bBase[2];
#pragma unroll
  for (int g=0; g<2; g++){
    int ch = g*256 + tid;
    int r = ch >> 3, c = ch & 7;
    bBase[g] = (long)(col0 + r)*K + (c ^ (r & 7))*8;
  }
  int raBase[4], rbBase[2];
#pragma unroll
  for (int i=0;i<4;i++)  raBase[i] = ((w&1)*64 + i*16 + (ln&15))*8;
#pragma unroll
  for (int j=0;j<2;j++)  rbBase[j] = ((w>>1)*32 + j*16 + (ln&15))*8;

  float4v acc[4][NJ] = {};

  auto issue = [&](int t, int slot){
    int k0 = t*64;
    char* sa = (char*)LDSB + slot*24576;
    char* sb = sa + 16384;
#pragma unroll
    for (int g=0; g<4; g++)
      GLL(A16 + aBase[g] + k0 + aCol[g], sa + g*4096 + w*1024);
#pragma unroll
    for (int g=0; g<2; g++)
      GLL(Wb + bBase[g] + k0, sb + g*4096 + w*1024);
  };

  issue(0, 0);
  issue(1, 1);
  issue(2, 2);

  int slot = 0;
  for (int t=0; t<NITER; t++){
    if (t+2 < NITER)      asm volatile("s_waitcnt vmcnt(12)" ::: "memory");
    else if (t+1 < NITER) asm volatile("s_waitcnt vmcnt(6)" ::: "memory");
    else                  asm volatile("s_waitcnt vmcnt(0)" ::: "memory");
    __builtin_amdgcn_s_barrier();
    asm volatile("" ::: "memory");
    const char* ab = (const char*)LDSB + slot*24576;
    const char* bb = ab + 16384;
#pragma unroll
    for (int s=0;s<2;s++){
      int xs = (s*4 + (ln>>4)) ^ (ln&7);
      short8 af[4], bf[NJ];
#pragma unroll
      for (int i=0;i<4;i++)  af[i] = *(const short8*)(ab + (raBase[i] + xs)*16);
#pragma unroll
      for (int j=0;j<NJ;j++) bf[j] = *(const short8*)(bb + (rbBase[j] + xs)*16);
#pragma unroll
      for (int i=0;i<4;i++)
#pragma unroll
        for (int j=0;j<NJ;j++)
          acc[i][j] = __builtin_amdgcn_mfma_f32_16x16x32_bf16(af[i], bf[j], acc[i][j], 0, 0, 0);
    }
    __builtin_amdgcn_s_barrier();
    asm volatile("" ::: "memory");
    if (t+3 < NITER) issue(t+3, slot);
    slot = (slot==2) ? 0 : slot+1;
  }

  float* Cf = (float*)C;
  unsigned short* Cb = (unsigned short*)C;
  if (outbf){
    int clBase = (w>>1)*32 + (ln & 15);
#pragma unroll
    for (int i=0;i<4;i++){
      int rlBase = (w&1)*64 + i*16 + (ln>>4)*4;
      int xr = ((rlBase>>2) & SWM) << 4;
#pragma unroll
      for (int j=0;j<NJ;j++){
        int cl = clBase + j*16;
        int colb = col0 + cl;
        float vv[4];
#pragma unroll
        for (int r=0;r<4;r++){
          float v = acc[i][j][r];
          if (bias) v += bias[colb];
          if (act){
            float z = 0.7978845608f * v * (1.f + 0.044715f*v*v);
            float e = __expf(2.f*z);
            v = v * (1.f - 1.f/(e + 1.f));
          }
          vv[r] = v;
        }
        unsigned p01 = cvtpk2(vv[0], vv[1]);
        unsigned p23 = cvtpk2(vv[2], vv[3]);
        int sc = cl ^ xr;
        LDSB[(rlBase+0)*TN + sc] = (unsigned short)p01;
        LDSB[(rlBase+1)*TN + sc] = (unsigned short)(p01>>16);
        LDSB[(rlBase+2)*TN + sc] = (unsigned short)p23;
        LDSB[(rlBase+3)*TN + sc] = (unsigned short)(p23>>16);
      }
    }
    __syncthreads();
    constexpr int CPR = TN/8;
#pragma unroll
    for (int e = 0; e < 128*CPR; e += 256){
      int idx = e + tid;
      int rl = idx / CPR, c8 = (idx % CPR)*8;
      int sc8 = c8 ^ (((rl>>2) & SWM) << 4);
      uint4 val = *(const uint4*)&LDSB[rl*TN + sc8];
      int grow = row0 + rl;
      int colb = col0 + c8;
      if (qkv){
        int bsel = colb >> 9;
        *(uint4*)&Cb[(size_t)bsel*bufstride + (size_t)grow*512 + (colb & 511)] = val;
      } else {
        *(uint4*)&Cb[(size_t)grow*N + colb] = val;
      }
    }
  } else {
    int colb0 = col0 + (w>>1)*32 + (ln & 15);
#pragma unroll
    for (int i=0;i<4;i++){
      int growb = row0 + (w&1)*64 + i*16 + (ln>>4)*4;
#pragma unroll
      for (int j=0;j<NJ;j++){
        int colb = colb0 + j*16;
#pragma unroll
        for (int r=0;r<4;r++){
          float v = acc[i][j][r];
          if (bias) v += bias[colb];
          if (act){
            float z = 0.7978845608f * v * (1.f + 0.044715f*v*v);
            float e = __expf(2.f*z);
            v = v * (1.f - 1.f/(e + 1.f));
          }
          Cf[(size_t)(growb+r)*N + colb] = v;
        }
      }
    }
  }
}

// =======================================================================
// bgemm2 (R9 form): bf16 MFMA GEMM, 128xTN tile, BK=64, single-buffered
// staging + conflict-free LDS-staged coalesced epilogue.
// Used for QKV fallback (A32), w1 (TN=128), conv (A16 via hb, or A32 fb).
// =======================================================================
template<int TN, int A32>
__global__ __launch_bounds__(256) void bgemm2(const void* __restrict__ Ain,
    const unsigned short* __restrict__ Wb, const float* __restrict__ bias, void* __restrict__ C,
    int N, int K, int L, int convmode, int act, int outbf, int qkv, size_t bufstride, int swz){
  constexpr int NJ = TN/32;
  constexpr int BR = TN/32;
  constexpr int SWM = TN/16 - 1;
  __shared__ unsigned short LDSBUF[128*64 + TN*64];
  unsigned short* As = LDSBUF;
  unsigned short* Bs = LDSBUF + 128*64;
  int tid = threadIdx.x;
  int w = tid >> 6, ln = tid & 63;

  int bx = blockIdx.x, by = blockIdx.y;
  if (swz){
    int XT = gridDim.x, YT = gridDim.y;
    int lid = by*XT + bx;
    int xcd = lid & 7, s = lid >> 3;
    int ych = YT >> 3;
    int CHv = ych < swz ? ych : swz;
    int yloc = s % CHv;
    int t2 = s / CHv;
    int xx = t2 % XT;
    int chunk = t2 / XT;
    by = xcd*ych + chunk*CHv + yloc;
    bx = xx;
  }
  int row0 = by*128, col0 = bx*TN;
  int KA = convmode ? 512 : K;

  long aBase[4], dPrev[4], dNext[4]; int aCol[4];
#pragma unroll
  for (int g=0; g<4; g++){
    int ch = g*256 + tid;
    int r = ch >> 3, c = ch & 7;
    int gc = c ^ (r & 7);
    int gr = row0 + r;
    aCol[g] = gc*8;
    aBase[g] = (long)gr * KA;
    if (convmode){
      int l = gr % L;
      dPrev[g] = (l==0)   ? (long)(L-1)*KA : -(long)KA;
      dNext[g] = (l==L-1) ? -(long)(L-1)*KA : (long)KA;
    } else { dPrev[g]=0; dNext[g]=0; }
  }
  long bBase[BR];
#pragma unroll
  for (int g=0; g<BR; g++){
    int ch = g*256 + tid;
    int r = ch >> 3, c = ch & 7;
    int gc = c ^ (r & 7);
    bBase[g] = (long)(col0 + r)*K + gc*8;
  }
  int raBase[4], rbBase[NJ];
#pragma unroll
  for (int i=0;i<4;i++)  raBase[i] = ((w&1)*64 + i*16 + (ln&15))*8;
#pragma unroll
  for (int j=0;j<NJ;j++) rbBase[j] = ((w>>1)*(TN/2) + j*16 + (ln&15))*8;

  float4v acc[4][NJ] = {};
  int nIter = K/64;
  const unsigned short* A16 = (const unsigned short*)Ain;
  const float* Af = (const float*)Ain;

  for (int it=0; it<nIter; it++){
    int k0 = it*64;
    int kk = convmode ? (k0 & 511) : k0;
    int seg = convmode ? (k0 >> 9) : 1;
    if (A32){
#pragma unroll
      for (int g=0; g<4; g++){
        long d = convmode ? ((seg==0) ? dPrev[g] : (seg==2 ? dNext[g] : 0)) : 0;
        const float* src = Af + aBase[g] + d + kk + aCol[g];
        float4 v0 = *(const float4*)src;
        float4 v1 = *(const float4*)(src+4);
        uint4 pk;
        pk.x = cvtpk2(v0.x, v0.y); pk.y = cvtpk2(v0.z, v0.w);
        pk.z = cvtpk2(v1.x, v1.y); pk.w = cvtpk2(v1.z, v1.w);
        *(uint4*)((char*)As + g*4096 + tid*16) = pk;
      }
    } else {
#pragma unroll
      for (int g=0; g<4; g++){
        long d = convmode ? ((seg==0) ? dPrev[g] : (seg==2 ? dNext[g] : 0)) : 0;
        GLL(A16 + aBase[g] + d + kk + aCol[g], (char*)As + g*4096 + w*1024);
      }
    }
#pragma unroll
    for (int g=0; g<BR; g++)
      GLL(Wb + bBase[g] + k0, (char*)Bs + g*4096 + w*1024);
    __syncthreads();
    const char* ab = (const char*)As;
    const char* bb = (const char*)Bs;
#pragma unroll
    for (int s=0;s<2;s++){
      int xs = (s*4 + (ln>>4)) ^ (ln&7);
      short8 af[4], bf[NJ];
#pragma unroll
      for (int i=0;i<4;i++)  af[i] = *(const short8*)(ab + (raBase[i] + xs)*16);
#pragma unroll
      for (int j=0;j<NJ;j++) bf[j] = *(const short8*)(bb + (rbBase[j] + xs)*16);
#pragma unroll
      for (int i=0;i<4;i++)
#pragma unroll
        for (int j=0;j<NJ;j++)
          acc[i][j] = __builtin_amdgcn_mfma_f32_16x16x32_bf16(af[i], bf[j], acc[i][j], 0, 0, 0);
    }
    __syncthreads();
  }

  float* Cf = (float*)C;
  unsigned short* Cb = (unsigned short*)C;
  if (outbf){
    int clBase = (w>>1)*(TN/2) + (ln & 15);
#pragma unroll
    for (int i=0;i<4;i++){
      int rlBase = (w&1)*64 + i*16 + (ln>>4)*4;
      int xr = ((rlBase>>2) & SWM) << 4;
#pragma unroll
      for (int j=0;j<NJ;j++){
        int cl = clBase + j*16;
        int colb = col0 + cl;
        float vv[4];
#pragma unroll
        for (int r=0;r<4;r++){
          float v = acc[i][j][r];
          if (bias) v += bias[colb];
          if (act){
            float z = 0.7978845608f * v * (1.f + 0.044715f*v*v);
            float e = __expf(2.f*z);
            v = v * (1.f - 1.f/(e + 1.f));
          }
          vv[r] = v;
        }
        unsigned p01 = cvtpk2(vv[0], vv[1]);
        unsigned p23 = cvtpk2(vv[2], vv[3]);
        int sc = cl ^ xr;
        LDSBUF[(rlBase+0)*TN + sc] = (unsigned short)p01;
        LDSBUF[(rlBase+1)*TN + sc] = (unsigned short)(p01>>16);
        LDSBUF[(rlBase+2)*TN + sc] = (unsigned short)p23;
        LDSBUF[(rlBase+3)*TN + sc] = (unsigned short)(p23>>16);
      }
    }
    __syncthreads();
    constexpr int CPR = TN/8;
#pragma unroll
    for (int e = 0; e < 128*CPR; e += 256){
      int idx = e + tid;
      int rl = idx / CPR, c8 = (idx % CPR)*8;
      int sc8 = c8 ^ (((rl>>2) & SWM) << 4);
      uint4 val = *(const uint4*)&LDSBUF[rl*TN + sc8];
      int grow = row0 + rl;
      int colb = col0 + c8;
      if (qkv){
        int bsel = colb >> 9;
        *(uint4*)&Cb[(size_t)bsel*bufstride + (size_t)grow*512 + (colb & 511)] = val;
      } else {
        *(uint4*)&Cb[(size_t)grow*N + colb] = val;
      }
    }
  } else {
    int colb0 = col0 + (w>>1)*(TN/2) + (ln & 15);
#pragma unroll
    for (int i=0;i<4;i++){
      int growb = row0 + (w&1)*64 + i*16 + (ln>>4)*4;
#pragma unroll
      for (int j=0;j<NJ;j++){
        int colb = colb0 + j*16;
#pragma unroll
        for (int r=0;r<4;r++){
          float v = acc[i][j][r];
          if (bias) v += bias[colb];
          if (act){
            float z = 0.7978845608f * v * (1.f + 0.044715f*v*v);
            float e = __expf(2.f*z);
            v = v * (1.f - 1.f/(e + 1.f));
          }
          Cf[(size_t)(growb+r)*N + colb] = v;
        }
      }
    }
  }
}

// ---------------- sample_m2: one wave per (b,l), all 8 heads; 16B/lane loads ----------------
__global__ __launch_bounds__(256) void sample_m2(const unsigned short* __restrict__ q,
    const unsigned short* __restrict__ k, const int* __restrict__ idx, float* __restrict__ m, int L, int u){
  int w = (blockIdx.x*256 + threadIdx.x) >> 6;
  int lane = threadIdx.x & 63;
  int l = w % L; int b = w / L;
  const unsigned short* qrow = q + (size_t)w*DM + lane*8;
  uint4 qq = *(const uint4*)qrow;
  float qv[8];
  qv[0]=b2f((unsigned short)(qq.x&0xffff)); qv[1]=b2f((unsigned short)(qq.x>>16));
  qv[2]=b2f((unsigned short)(qq.y&0xffff)); qv[3]=b2f((unsigned short)(qq.y>>16));
  qv[4]=b2f((unsigned short)(qq.z&0xffff)); qv[5]=b2f((unsigned short)(qq.z>>16));
  qv[6]=b2f((unsigned short)(qq.w&0xffff)); qv[7]=b2f((unsigned short)(qq.w>>16));
  const unsigned short* kb = k + (size_t)b*L*DM + lane*8;
  const int* ip = idx + (size_t)l*u;
  float mx = -1e30f, sum = 0.f;
  for (int s=0; s<u; s++){
    int kp = ip[s];
    uint4 kk = *(const uint4*)(kb + (size_t)kp*DM);
    float p;
    p  = qv[0]*b2f((unsigned short)(kk.x&0xffff)) + qv[1]*b2f((unsigned short)(kk.x>>16));
    p += qv[2]*b2f((unsigned short)(kk.y&0xffff)) + qv[3]*b2f((unsigned short)(kk.y>>16));
    p += qv[4]*b2f((unsigned short)(kk.z&0xffff)) + qv[5]*b2f((unsigned short)(kk.z>>16));
    p += qv[6]*b2f((unsigned short)(kk.w&0xffff)) + qv[7]*b2f((unsigned short)(kk.w>>16));
    p += __shfl_xor(p, 1); p += __shfl_xor(p, 2); p += __shfl_xor(p, 4);
    mx = fmaxf(mx, p); sum += p;
  }
  if ((lane & 7) == 0){
    int hh = lane >> 3;
    m[((size_t)b*8 + hh)*L + l] = mx - sum/(float)u;
  }
}

// ---------------- iterative top-u argmax per (b,h): register-resident, wave-shuffle reduce ----------------
template<int NS>
__global__ __launch_bounds__(256) void topk_kernel(const float* __restrict__ m, int* __restrict__ top, int L, int u){
  int bh = blockIdx.x;
  const float* mm = m + (size_t)bh*L;
  int t = threadIdx.x;
  float v[NS];
#pragma unroll
  for (int s=0; s<NS; s++) v[s] = mm[s*256 + t];
  __shared__ float rv[4];
  __shared__ int   ri[4];
  for (int it=0; it<u; it++){
    float bv = -1e30f; int bi = 0x7fffffff;
#pragma unroll
    for (int s=0; s<NS; s++){
      float x = v[s]; int i = s*256 + t;
      if (x > bv || (x == bv && i < bi)) { bv = x; bi = i; }
    }
#pragma unroll
    for (int off=32; off; off>>=1){
      float ov = __shfl_xor(bv, off); int oi = __shfl_xor(bi, off);
      if (ov > bv || (ov == bv && oi < bi)) { bv = ov; bi = oi; }
    }
    if ((t & 63) == 0){ rv[t>>6] = bv; ri[t>>6] = bi; }
    __syncthreads();
    bv = rv[0]; bi = ri[0];
#pragma unroll
    for (int k2=1; k2<4; k2++){
      float ov = rv[k2]; int oi = ri[k2];
      if (ov > bv || (ov == bv && oi < bi)) { bv = ov; bi = oi; }
    }
    if (t == 0) top[bh*u + it] = bi;
    if ((bi & 255) == t){
      int slot = bi >> 8;
#pragma unroll
      for (int s=0; s<NS; s++) if (s == slot) v[s] = -1e31f;
    }
    __syncthreads();
  }
}

// ---------------- column mean, two-stage ----------------
#define CMC 32
__global__ __launch_bounds__(256) void colmean1(const float* __restrict__ src, float* __restrict__ part, int L){
  int b = blockIdx.x, ch = blockIdx.y;
  int rpb = L / CMC;
  int t = threadIdx.x;
  const float* p = src + ((size_t)b*L + (size_t)ch*rpb)*DM;
  float s0 = 0.f, s1 = 0.f;
  for (int r=0; r<rpb; r++){ s0 += p[(size_t)r*DM + t]; s1 += p[(size_t)r*DM + t + 256]; }
  float* o = part + ((size_t)b*CMC + ch)*DM;
  o[t] = s0; o[t+256] = s1;
}
__global__ __launch_bounds__(256) void colmean2(const float* __restrict__ part, float* __restrict__ dst, int L){
  int i = blockIdx.x*256 + threadIdx.x;
  int d = i % DM, b = i / DM;
  float s = 0.f;
  for (int c=0; c<CMC; c++) s += part[((size_t)b*CMC + c)*DM + d];
  dst[i] = s / (float)L;
}

// ---------------- tiny fp32 GEMM: one block per row ----------------
__global__ __launch_bounds__(256) void tiny_gemm(const float* __restrict__ A, const float* __restrict__ W,
    const float* __restrict__ bias, float* __restrict__ C, int N, int K){
  int row = blockIdx.x;
  const float* ar = A + (size_t)row*K;
  __shared__ float as[DM];
  for (int k=threadIdx.x; k<K; k+=256) as[k] = ar[k];
  __syncthreads();
  for (int n = threadIdx.x; n < N; n += 256){
    float acc = bias ? bias[n] : 0.f;
    const float* wr = W + (size_t)n*K;
    for (int k=0; k<K; k++) acc += as[k]*wr[k];
    C[(size_t)row*N + n] = acc;
  }
}

// ---------------- gather q rows for top queries (bf16 q -> fp32 qred) ----------------
__global__ __launch_bounds__(256) void qred_kernel(const unsigned short* __restrict__ q, const int* __restrict__ top,
    float* __restrict__ qred, int L, int u, int n){
  int i = blockIdx.x*256 + threadIdx.x;
  if (i >= n) return;
  int d = i & 63; int rest = i >> 6; int j = rest % u; int bh = rest / u;
  int hh = bh & 7; int b = bh >> 3;
  int pos = top[bh*u + j];
  qred[i] = b2f(q[((size_t)b*L + pos)*DM + hh*DH + d]);
}

// =======================================================================
// flash_attn: fused QK^T -> online softmax -> PV, key-split partials.
// =======================================================================
#define FKT 128
__global__ __launch_bounds__(256) void flash_attn(const float* __restrict__ qred,
    const unsigned short* __restrict__ kbuf, const unsigned short* __restrict__ vbuf,
    float* __restrict__ partM, float* __restrict__ partL, float* __restrict__ partA,
    int L, int u, int KS){
  int ks = blockIdx.x, bh = blockIdx.y; int b = bh >> 3, h = bh & 7;
  int t = threadIdx.x;
  __shared__ float Qs[38*64];              // 9.7 KB
  __shared__ unsigned short Ks[FKT*64];    // 16 KB (xor-swizzled chunks)
  __shared__ unsigned short Vs[FKT*64];    // 16 KB (natural)
  __shared__ float Ss[38*FKT];             // 19.4 KB
  for (int i=t;i<u*64;i+=256) Qs[i] = qred[(size_t)bh*u*64 + i];
  int lane = t & 63, w = t >> 6;
  float rm[10], rl[10], racc[10];
#pragma unroll
  for (int j=0;j<10;j++){ rm[j]=-1e30f; rl[j]=0.f; racc[j]=0.f; }
  int nk = L / KS;
  int kbase = ks*nk;
  int key = t & 127, rh = t >> 7;
  for (int kt = 0; kt < nk; kt += FKT){
    __syncthreads();
    for (int e = t; e < FKT*8; e += 256){   // chunk id: k=e>>3, c=e&7 (16B chunks)
      int k = e >> 3, c = e & 7;
      size_t gidx = ((size_t)(b*L + kbase + kt + k))*DM + h*DH + c*8;
      *(uint4*)((char*)Ks + (size_t)(k*8 + (c ^ (k&7)))*16) = *(const uint4*)(kbuf + gidx);
      *(uint4*)((char*)Vs + (size_t)e*16) = *(const uint4*)(vbuf + gidx);
    }
    __syncthreads();
    // scores: thread (key, rh) computes rows rh, rh+2, ...
    for (int r = rh; r < u; r += 2){
      const float4* q4 = (const float4*)(Qs + r*64);
      float acc = 0.f;
#pragma unroll
      for (int c=0;c<8;c++){
        short8 kk = *(const short8*)((char*)Ks + (size_t)(key*8 + (c ^ (key&7)))*16);
        float4 qa = q4[c*2], qb = q4[c*2+1];
        acc += qa.x*b2f((unsigned short)kk[0]) + qa.y*b2f((unsigned short)kk[1])
             + qa.z*b2f((unsigned short)kk[2]) + qa.w*b2f((unsigned short)kk[3]);
        acc += qb.x*b2f((unsigned short)kk[4]) + qb.y*b2f((unsigned short)kk[5])
             + qb.z*b2f((unsigned short)kk[6]) + qb.w*b2f((unsigned short)kk[7]);
      }
      Ss[r*FKT + key] = acc * 0.125f;
    }
    __syncthreads();
    // online softmax + PV: wave w owns rows w, w+4, ... (lane = output dim)
    int j = 0;
    for (int r = w; r < u; r += 4, j++){
      float s0 = Ss[r*FKT + lane], s1 = Ss[r*FKT + 64 + lane];
      float mx = fmaxf(s0, s1);
#pragma unroll
      for (int off=32; off; off>>=1) mx = fmaxf(mx, __shfl_xor(mx, off));
      float newm = fmaxf(rm[j], mx);
      float scale = expf(rm[j] - newm);
      float p0 = expf(s0 - newm), p1 = expf(s1 - newm);
      float ps = p0 + p1;
#pragma unroll
      for (int off=32; off; off>>=1) ps += __shfl_xor(ps, off);
      rl[j] = rl[j]*scale + ps;
      rm[j] = newm;
      Ss[r*FKT + lane] = p0; Ss[r*FKT + 64 + lane] = p1;
      float a = racc[j]*scale;
      for (int k=0;k<FKT;k+=4){
        float pa = Ss[r*FKT+k], pb = Ss[r*FKT+k+1], pc = Ss[r*FKT+k+2], pd = Ss[r*FKT+k+3];
        a += pa*b2f(Vs[(k+0)*64+lane]) + pb*b2f(Vs[(k+1)*64+lane])
           + pc*b2f(Vs[(k+2)*64+lane]) + pd*b2f(Vs[(k+3)*64+lane]);
      }
      racc[j] = a;
    }
  }
  int j = 0;
  for (int r = w; r < u; r += 4, j++){
    size_t base = ((size_t)bh*KS + ks)*u + r;
    if (lane == 0){ partM[base] = rm[j]; partL[base] = rl[j]; }
    partA[base*64 + lane] = racc[j];
  }
}

// ---------------- merge key-split partials -> ctxt ----------------
__global__ __launch_bounds__(256) void flash_merge(const float* __restrict__ partM, const float* __restrict__ partL,
    const float* __restrict__ partA, float* __restrict__ ctxt, int u, int KS, int n){
  int i = blockIdx.x*256 + threadIdx.x;
  if (i >= n) return;
  int nn = i & 63; int rest = i >> 6; int r = rest % u; int bhl = rest / u;
  size_t base0 = ((size_t)bhl*KS)*u + r;
  float gm = -1e30f;
  for (int s=0;s<KS;s++) gm = fmaxf(gm, partM[base0 + (size_t)s*u]);
  float lt = 0.f, at = 0.f;
  for (int s=0;s<KS;s++){
    float e = expf(partM[base0 + (size_t)s*u] - gm);
    lt += partL[base0 + (size_t)s*u]*e;
    at += partA[(base0 + (size_t)s*u)*64 + nn]*e;
  }
  ctxt[i] = at / lt;
}

// ---------------- sparse correction: h[b,pos] += (ctxt - vmean_slice)@wo_slice^T ----------------
__global__ __launch_bounds__(256) void scatter_delta(const float* __restrict__ ctxt, const float* __restrict__ vmean,
    const float* __restrict__ wo, const int* __restrict__ top, float* __restrict__ h, int L, int u){
  int bid = blockIdx.x;
  int j = bid % u; int bh = bid / u; int hh = bh & 7; int b = bh >> 3;
  int pos = top[bh*u + j];
  __shared__ float delta[DH];
  int t = threadIdx.x;
  if (t < DH) delta[t] = ctxt[(size_t)(bh*u + j)*DH + t] - vmean[b*DM + hh*DH + t];
  __syncthreads();
  float* hrow = h + ((size_t)b*L + pos)*DM;
  const float* wbase = wo + hh*DH;
  for (int n = t; n < DM; n += 256){
    float acc = 0.f;
    const float* wr = wbase + (size_t)n*DM;
#pragma unroll
    for (int dd=0; dd<DH; dd++) acc += delta[dd] * wr[dd];
    atomicAdd(&hrow[n], acc);
  }
}

// ---------------- LayerNorm D=512, wave-per-row; optional bf16 shadow out ----------------
__global__ __launch_bounds__(256) void ln_kernel(const float* __restrict__ X, const void* __restrict__ Yadd,
    int yb, const float* __restrict__ g, const float* __restrict__ bta, void* __restrict__ Out, int ob,
    const float* __restrict__ cwv, int Lrow, int row0g, unsigned short* __restrict__ hbo){
  int w = threadIdx.x >> 6, lane = threadIdx.x & 63;
  size_t row = (size_t)blockIdx.x*4 + w;
  int d0 = lane*8;
  const float* xr = X + row*DM + d0;
  float4 a = *(const float4*)xr;
  float4 b = *(const float4*)(xr+4);
  float v[8] = {a.x,a.y,a.z,a.w,b.x,b.y,b.z,b.w};
  if (cwv){
    int bb = (int)(((size_t)row0g + row) / (size_t)Lrow);
    const float* cp = cwv + (size_t)bb*DM + d0;
    float4 c0 = *(const float4*)cp, c1 = *(const float4*)(cp+4);
    v[0]+=c0.x; v[1]+=c0.y; v[2]+=c0.z; v[3]+=c0.w;
    v[4]+=c1.x; v[5]+=c1.y; v[6]+=c1.z; v[7]+=c1.w;
  }
  if (Yadd){
    if (yb){
      const unsigned short* yr = (const unsigned short*)Yadd + row*DM + d0;
      uint4 yv = *(const uint4*)yr;
      v[0]+=b2f((unsigned short)(yv.x&0xffff)); v[1]+=b2f((unsigned short)(yv.x>>16));
      v[2]+=b2f((unsigned short)(yv.y&0xffff)); v[3]+=b2f((unsigned short)(yv.y>>16));
      v[4]+=b2f((unsigned short)(yv.z&0xffff)); v[5]+=b2f((unsigned short)(yv.z>>16));
      v[6]+=b2f((unsigned short)(yv.w&0xffff)); v[7]+=b2f((unsigned short)(yv.w>>16));
    } else {
      const float* yr = (const float*)Yadd + row*DM + d0;
      float4 y0 = *(const float4*)yr, y1 = *(const float4*)(yr+4);
      v[0]+=y0.x; v[1]+=y0.y; v[2]+=y0.z; v[3]+=y0.w;
      v[4]+=y1.x; v[5]+=y1.y; v[6]+=y1.z; v[7]+=y1.w;
    }
  }
  float s = 0.f, q = 0.f;
#pragma unroll
  for (int i=0;i<8;i++){ s += v[i]; q += v[i]*v[i]; }
#pragma unroll
  for (int off=32; off; off>>=1){ s += __shfl_xor(s,off); q += __shfl_xor(q,off); }
  float mu  = s * (1.0f/DM);
  float var = q * (1.0f/DM) - mu*mu;
  float r = rsqrtf(var + 1e-5f);
  const float* gp = g + d0; const float* bp = bta + d0;
  float4 g0 = *(const float4*)gp, g1 = *(const float4*)(gp+4);
  float4 b0 = *(const float4*)bp, b1 = *(const float4*)(bp+4);
  float gg[8] = {g0.x,g0.y,g0.z,g0.w,g1.x,g1.y,g1.z,g1.w};
  float bb2[8] = {b0.x,b0.y,b0.z,b0.w,b1.x,b1.y,b1.z,b1.w};
  float o[8];
#pragma unroll
  for (int i=0;i<8;i++) o[i] = (v[i]-mu)*r*gg[i] + bb2[i];
  if (ob){
    uint4 pk;
    pk.x = cvtpk2(o[0],o[1]); pk.y = cvtpk2(o[2],o[3]);
    pk.z = cvtpk2(o[4],o[5]); pk.w = cvtpk2(o[6],o[7]);
    *(uint4*)((unsigned short*)Out + row*DM + d0) = pk;
  } else {
    float* Of = (float*)Out + row*DM + d0;
    *(float4*)Of     = make_float4(o[0],o[1],o[2],o[3]);
    *(float4*)(Of+4) = make_float4(o[4],o[5],o[6],o[7]);
    if (hbo){
      uint4 pk;
      pk.x = cvtpk2(o[0],o[1]); pk.y = cvtpk2(o[2],o[3]);
      pk.z = cvtpk2(o[4],o[5]); pk.w = cvtpk2(o[6],o[7]);
      *(uint4*)&hbo[row*DM + d0] = pk;
    }
  }
}

// ---------------- BN partial sums over bf16 conv output (grid: 8 x 128) ----------------
__global__ __launch_bounds__(256) void bnstat1(const unsigned short* __restrict__ C, float* __restrict__ partS,
                                               float* __restrict__ partQ, int rpb){
  int chb = blockIdx.x;
  int mb  = blockIdx.y;
  int g = threadIdx.x >> 6, c = threadIdx.x & 63;
  int ch = chb*64 + c;
  float s = 0.f, q = 0.f;
  int r0 = mb * rpb;
  for (int r = r0 + g; r < r0 + rpb; r += 4){
    float v = b2f(C[(size_t)r*DM + ch]); s += v; q += v*v;
  }
  __shared__ float ls[4][64], lq[4][64];
  ls[g][c] = s; lq[g][c] = q;
  __syncthreads();
  if (g == 0){
    s = ls[0][c]+ls[1][c]+ls[2][c]+ls[3][c];
    q = lq[0][c]+lq[1][c]+lq[2][c]+lq[3][c];
    partS[(size_t)mb*DM + ch] = s;
    partQ[(size_t)mb*DM + ch] = q;
  }
}
__global__ __launch_bounds__(256) void bnstat2(const float* __restrict__ partS, const float* __restrict__ partQ,
                                               float* __restrict__ stats, int NB, int M){
  int ch = blockIdx.x*256 + threadIdx.x;
  if (ch >= DM) return;
  float s = 0.f, q = 0.f;
  for (int mb=0; mb<NB; mb++){
    s += partS[(size_t)mb*DM + ch];
    q += partQ[(size_t)mb*DM + ch];
  }
  float mu = s / (float)M;
  stats[ch] = mu;
  stats[DM + ch] = q / (float)M - mu*mu;
}

// ---------------- BN + ELU + maxpool(3,2); optional bf16 shadow hb ----------------
__global__ __launch_bounds__(256) void bnpool(const unsigned short* __restrict__ C, const float* __restrict__ stats,
    const float* __restrict__ g, const float* __restrict__ bta, float* __restrict__ Out,
    unsigned short* __restrict__ hb, int L, int Lo){
  size_t i = (size_t)blockIdx.x*256 + threadIdx.x;
  int ch = (int)(i % DM);
  size_t r = i / DM;
  int lo = (int)(r % Lo);
  int b  = (int)(r / Lo);
  float mu = stats[ch];
  float rstd = rsqrtf(stats[DM+ch] + 1e-5f);
  float gg = g[ch], bb = bta[ch];
  float best = -1e30f;
#pragma unroll
  for (int t=-1; t<=1; t++){
    int li = 2*lo + t;
    if (li >= 0 && li < L){
      float v = (b2f(C[((size_t)b*L + li)*DM + ch]) - mu)*rstd*gg + bb;
      v = v > 0.f ? v : expm1f(v);
      best = fmaxf(best, v);
    }
  }
  size_t oidx = ((size_t)b*Lo + lo)*DM + ch;
  Out[oidx] = best;
  if (hb) hb[oidx] = f2b(best);
}

// ---------------- final: LN(last row) @ proj^T + proj_b + skip ----------------
__global__ __launch_bounds__(128) void final_kernel(const float* __restrict__ h, const float* __restrict__ x,
    const float* __restrict__ fg, const float* __restrict__ fb, const float* __restrict__ pw,
    const float* __restrict__ pb, const float* __restrict__ sw, const float* __restrict__ sb,
    float* __restrict__ out, int Lf, int L0){
  int b = blockIdx.x;
  const float* row = h + ((size_t)b*Lf + (Lf-1))*DM;
  __shared__ float xn[DM];
  __shared__ float rs[2], rq[2];
  int t = threadIdx.x;
  float v[4]; float s = 0.f, q = 0.f;
#pragma unroll
  for (int i=0;i<4;i++){ v[i] = row[t + i*128]; s += v[i]; q += v[i]*v[i]; }
#pragma unroll
  for (int off=32; off; off>>=1){ s += __shfl_xor(s,off); q += __shfl_xor(q,off); }
  if ((t & 63) == 0){ rs[t>>6] = s; rq[t>>6] = q; }
  __syncthreads();
  s = rs[0]+rs[1]; q = rq[0]+rq[1];
  float mu = s*(1.0f/DM), var = q*(1.0f/DM) - mu*mu;
  float r = rsqrtf(var + 1e-5f);
#pragma unroll
  for (int i=0;i<4;i++){ int d = t + i*128; xn[d] = (v[i]-mu)*r*fg[d] + fb[d]; }
  __syncthreads();
  if (t < 96){
    float acc = pb[t] + sb[t];
    const float* xr = x + ((size_t)b*L0 + (L0-1))*7;
#pragma unroll
    for (int c=0;c<7;c++) acc += xr[c]*sw[t*7+c];
    for (int d=0; d<DM; d++) acc += xn[d]*pw[(size_t)t*DM + d];
    out[b*96 + t] = acc;
  }
}

// =======================================================================
extern "C" void kernel_launch(void* const* d_in, const int* in_sizes, int n_in,
                              void* d_out, int out_size, void* d_ws, size_t ws_size,
                              hipStream_t stream){
  const float* x    = (const float*)d_in[0];
  const float* skw  = (const float*)d_in[1];
  const float* skb  = (const float*)d_in[2];
  const float* tcw  = (const float*)d_in[3];
  const float* wq   = (const float*)d_in[4];
  const float* bq   = (const float*)d_in[5];
  const float* wk   = (const float*)d_in[6];
  const float* bk   = (const float*)d_in[7];
  const float* wv   = (const float*)d_in[8];
  const float* bv   = (const float*)d_in[9];
  const float* wo   = (const float*)d_in[10];
  const float* bo   = (const float*)d_in[11];
  const float* w1   = (const float*)d_in[12];
  const float* b1   = (const float*)d_in[13];
  const float* w2   = (const float*)d_in[14];
  const float* b2   = (const float*)d_in[15];
  const float* ln1g = (const float*)d_in[16];
  const float* ln1b = (const float*)d_in[17];
  const float* ln2g = (const float*)d_in[18];
  const float* ln2b = (const float*)d_in[19];
  const float* dcw  = (const float*)d_in[20];
  const float* dcb  = (const float*)d_in[21];
  const float* bng  = (const float*)d_in[22];
  const float* bnb  = (const float*)d_in[23];
  const float* flg  = (const float*)d_in[24];
  const float* flb  = (const float*)d_in[25];
  const float* pw   = (const float*)d_in[26];
  const float* pb   = (const float*)d_in[27];

  const int B = 32, L0 = 2048, DFF = 2048;
  const int RG = 16384;
  const int RF = 8192;
  char* ws = (char*)d_ws;
  const size_t SZH  = (size_t)B*L0*DM*sizeof(float);
  const size_t SLOT = (size_t)RG*DM*sizeof(unsigned short);

  const size_t WBSZ = (size_t)(3*DM*DM + 2*DFF*DM + 3*DM*DM)*2;
  size_t small_bytes = (size_t)L0*40*4
                     + (size_t)RG*8*4
                     + (size_t)B*8*40*4
                     + (size_t)32*8*40*64*4
                     + (size_t)32*8*40*64*4
                     + 3*(size_t)B*DM*4
                     + 2*(size_t)128*DM*4
                     + (size_t)2*DM*4
                     + (size_t)1536*4
                     + (size_t)B*CMC*DM*4
                     + (size_t)L0*DM*4
                     + (size_t)21*DM*4;
  size_t base_bytes = SZH + 4*SLOT + WBSZ + small_bytes;
  if (ws_size < base_bytes) return;
  // optional bf16 shadow of h (64 MB): pipelined QKV + bf16 conv A
  size_t hb_off = (base_bytes + 255) & ~(size_t)255;
  size_t HBSZ = (size_t)B*L0*DM*2;
  int has_hb = (ws_size >= hb_off + HBSZ) ? 1 : 0;
  unsigned short* hb = has_hb ? (unsigned short*)(ws + hb_off) : nullptr;

  float*          h   = (float*)(ws);
  unsigned short* P0  = (unsigned short*)(ws + SZH);
  unsigned short* P1  = (unsigned short*)(ws + SZH + SLOT);
  unsigned short* P2  = (unsigned short*)(ws + SZH + 2*SLOT);
  unsigned short* P3  = (unsigned short*)(ws + SZH + 3*SLOT);
  unsigned short* wb  = (unsigned short*)(ws + SZH + 4*SLOT);
  unsigned short* wqb = wb;
  unsigned short* w1b = wqb + (size_t)3*DM*DM;
  unsigned short* w2b = w1b + (size_t)DFF*DM;
  unsigned short* wtapK= w2b + (size_t)DM*DFF;
  char* sm = ws + SZH + 4*SLOT + WBSZ;
  int*   idx_buf  = (int*)sm;
  float* m_buf    = (float*)(sm + (size_t)L0*40*4);
  int*   top_all  = (int*)((char*)m_buf + (size_t)RG*8*4);
  float* qred_loc = (float*)((char*)top_all + (size_t)B*8*40*4);
  float* ctxt_all = qred_loc + (size_t)32*8*40*64;
  float* hm       = ctxt_all + (size_t)32*8*40*64;
  float* vmean    = hm + (size_t)B*DM;
  float* cw       = vmean + (size_t)B*DM;
  float* partS    = cw + (size_t)B*DM;
  float* partQ    = partS + (size_t)128*DM;
  float* stats    = partQ + (size_t)128*DM;
  float* bqkv     = stats + (size_t)2*DM;
  float* partC    = bqkv + (size_t)1536;
  float* pe_buf   = partC + (size_t)B*CMC*DM;
  float* tcwT     = pe_buf + (size_t)L0*DM;

  // flash partials live in P0 (free during attention)
  float* fpM = (float*)P0;                       // 256*40
  float* fpL = fpM + (size_t)256*40;             // 256*40
  float* fpA = fpL + (size_t)256*40;             // 256*40*64 (~2.6 MB)

  auto conv_b = [&](const float* src, unsigned short* dst, size_t n){
    f2b_vec<<<(int)((n/4 + 255)/256), 256, 0, stream>>>(src, dst, (int)(n/4));
  };

  pe_kernel<<<(int)(((size_t)L0*DM)/256), 256, 0, stream>>>(pe_buf, L0);
  packtcw<<<(21*DM + 255)/256, 256, 0, stream>>>(tcw, tcwT);
  embed2<<<B*L0, 256, 0, stream>>>(x, tcwT, pe_buf, h, hb, L0);

  int L = L0;
  for (int layer = 0; layer < 3; layer++){
    int M = B * L;
    int u = (int)(5.0 * log((double)L + 1.0));   // 38 / 34 / 31
    int G = RG / L;
    int nG = M / RG;
    int KS = L / 512;                            // 4 / 2 / 1 key-splits
    const float* wv_i = wv + (size_t)layer*DM*DM;  const float* bv_i = bv + (size_t)layer*DM;
    const float* wo_i = wo + (size_t)layer*DM*DM;  const float* bo_i = bo + (size_t)layer*DM;
    const float* b1_i = b1 + (size_t)layer*DFF;
    const float* b2_i = b2 + (size_t)layer*DM;

    conv_b(wq + (size_t)layer*DM*DM, wqb,                    (size_t)DM*DM);
    conv_b(wk + (size_t)layer*DM*DM, wqb + (size_t)DM*DM,    (size_t)DM*DM);
    conv_b(wv_i,                     wqb + (size_t)2*DM*DM,  (size_t)DM*DM);
    conv_b(w1 + (size_t)layer*DFF*DM, w1b, (size_t)DFF*DM);
    conv_b(w2 + (size_t)layer*DM*DFF, w2b, (size_t)DM*DFF);
    catb_kernel<<<6, 256, 0, stream>>>(bq + (size_t)layer*DM, bk + (size_t)layer*DM, bv_i, bqkv);
    if (layer < 2)
      packconv<<<(3*DM*DM + 255)/256, 256, 0, stream>>>(dcw + (size_t)layer*DM*DM*3, wtapK);

    unsigned ka = 0u, kb2 = (unsigned)layer;
    tf2x32(0u, 42u, ka, kb2);
    unsigned a0 = 0u, a1 = 2u;  tf2x32(ka, kb2, a0, a1);
    unsigned c0 = 1u, c1 = 3u;  tf2x32(ka, kb2, c0, c1);
    int S2 = L * u / 2;
    idx_kernel<<<(S2 + 255)/256, 256, 0, stream>>>(idx_buf, a1, c1, S2, L-1);

    for (int g = 0; g < nG; g++){
      const float* hg = h + (size_t)g*RG*DM;
      if (has_hb){
        bgemm_dp<8><<<dim3(24, RG/128), 256, 0, stream>>>(hb + (size_t)g*RG*DM, wqb, bqkv, P1,
            1536, 0, 1, 1, (size_t)RG*DM, 16);
      } else {
        bgemm2<128,1><<<dim3(12, RG/128), 256, 0, stream>>>(hg, wqb, bqkv, P1,
            1536, 512, L, 0, 0, 1, 1, (size_t)RG*DM, 16);
      }
      sample_m2<<<RG/4, 256, 0, stream>>>(P1, P2, idx_buf, m_buf, L, u);
      int* top_g = top_all + (size_t)g*G*8*u;
      if (L == 2048)      topk_kernel<8><<<G*8, 256, 0, stream>>>(m_buf, top_g, L, u);
      else if (L == 1024) topk_kernel<4><<<G*8, 256, 0, stream>>>(m_buf, top_g, L, u);
      else                topk_kernel<2><<<G*8, 256, 0, stream>>>(m_buf, top_g, L, u);
      int nqr = G*8*u*DH;
      qred_kernel<<<(nqr + 255)/256, 256, 0, stream>>>(P1, top_g, qred_loc, L, u, nqr);

      flash_attn<<<dim3(KS, G*8), 256, 0, stream>>>(qred_loc, P2, P3, fpM, fpL, fpA, L, u, KS);
      int nmg = G*8*u*64;
      flash_merge<<<(nmg + 255)/256, 256, 0, stream>>>(fpM, fpL, fpA,
          ctxt_all + (size_t)g*G*8*u*64, u, KS, nmg);
    }

    // vmean = (mean_L h)@wv^T + bv ; cw = vmean@wo^T + bo (exact fp32 identity)
    colmean1<<<dim3(B, CMC), 256, 0, stream>>>(h, partC, L);
    colmean2<<<B*DM/256, 256, 0, stream>>>(partC, hm, L);
    tiny_gemm<<<B, 256, 0, stream>>>(hm, wv_i, bv_i, vmean, DM, DM);
    tiny_gemm<<<B, 256, 0, stream>>>(vmean, wo_i, bo_i, cw, DM, DM);

    scatter_delta<<<B*8*u, 256, 0, stream>>>(ctxt_all, vmean, wo_i, top_all, h, L, u);

    unsigned short* ybuf = P0;
    unsigned short* mid  = P1;
    unsigned short* y2b  = P0 + (size_t)RF*DM;
    const float* l1g = ln1g + (size_t)layer*DM; const float* l1b = ln1b + (size_t)layer*DM;
    const float* l2g = ln2g + (size_t)layer*DM; const float* l2b = ln2b + (size_t)layer*DM;
    int need_hb_conv = (layer < 2) && has_hb;
    for (int r0 = 0; r0 < M; r0 += RF){
      ln_kernel<<<RF/4, 256, 0, stream>>>(h + (size_t)r0*DM, nullptr, 0, l1g, l1b, ybuf, 1, cw, L, r0, nullptr);
      bgemm2<128,0><<<dim3(16, RF/128), 256, 0, stream>>>(ybuf, w1b, b1_i, mid,
          2048, 512, L, 0, 1, 1, 0, 0, 8);
      bgemm_dp<32><<<dim3(8, RF/128), 256, 0, stream>>>(mid, w2b, b2_i, y2b,
          512, 0, 1, 0, 0, 8);
      ln_kernel<<<RF/4, 256, 0, stream>>>(h + (size_t)r0*DM, y2b, 1, l2g, l2b, h + (size_t)r0*DM, 0, cw, L, r0,
          need_hb_conv ? (hb + (size_t)r0*DM) : nullptr);
    }

    if (layer < 2){
      const float* db = dcb + (size_t)layer*DM;
      unsigned short* convb = P0;
      if (has_hb){
        bgemm2<128,0><<<dim3(4, M/128), 256, 0, stream>>>(hb, wtapK, db, convb,
            512, 1536, L, 1, 0, 1, 0, 0, 16);
      } else {
        bgemm2<128,1><<<dim3(4, M/128), 256, 0, stream>>>(h, wtapK, db, convb,
            512, 1536, L, 1, 0, 1, 0, 0, 16);
      }
      bnstat1<<<dim3(8, 128), 256, 0, stream>>>(convb, partS, partQ, M/128);
      bnstat2<<<2, 256, 0, stream>>>(partS, partQ, stats, 128, M);
      int Lo = L/2;
      bnpool<<<(int)(((size_t)B*Lo*DM)/256), 256, 0, stream>>>(convb, stats,
          bng + (size_t)layer*DM, bnb + (size_t)layer*DM, h, hb, L, Lo);
      L = Lo;
    }
  }

  final_kernel<<<B, 128, 0, stream>>>(h, x, flg, flb, pw, pb, skw, skb, (float*)d_out, L, L0);
}

// Round 13
// 4681.276 us; speedup vs baseline: 1.0213x; 1.0213x over previous
//
#include <hip/hip_runtime.h>
#include <cmath>

#define DM 512
#define DH 64

typedef __attribute__((ext_vector_type(8))) short short8;
typedef __attribute__((ext_vector_type(4))) float float4v;

__device__ inline float b2f(unsigned short u){
  union{unsigned int i; float f;} z; z.i = ((unsigned)u)<<16; return z.f;
}
__device__ inline unsigned short f2b(float f){
  unsigned int x = __float_as_uint(f);
  return (unsigned short)((x + 0x7fffu + ((x>>16)&1u)) >> 16);   // RNE
}
// HW packed RNE convert: lo16 = bf16(a), hi16 = bf16(b)
__device__ inline unsigned cvtpk2(float a, float b){
  unsigned r; asm("v_cvt_pk_bf16_f32 %0, %1, %2" : "=v"(r) : "v"(a), "v"(b)); return r;
}

#define GLL(gp, lp) __builtin_amdgcn_global_load_lds((const __attribute__((address_space(1))) void*)(gp), \
    (__attribute__((address_space(3))) void*)(lp), 16, 0, 0)

// ---------------- Threefry-2x32-20 (matches jax.random) ----------------
__host__ __device__ inline void tf2x32(unsigned k0, unsigned k1, unsigned& x0, unsigned& x1){
  const unsigned ks0=k0, ks1=k1, ks2=k0^k1^0x1BD11BDAu;
  x0 += ks0; x1 += ks1;
#define TF_ROT(r) { x0 += x1; x1 = (x1<<(r))|(x1>>(32-(r))); x1 ^= x0; }
  TF_ROT(13) TF_ROT(15) TF_ROT(26) TF_ROT(6)
  x0 += ks1; x1 += ks2 + 1u;
  TF_ROT(17) TF_ROT(29) TF_ROT(16) TF_ROT(24)
  x0 += ks2; x1 += ks0 + 2u;
  TF_ROT(13) TF_ROT(15) TF_ROT(26) TF_ROT(6)
  x0 += ks0; x1 += ks1 + 3u;
  TF_ROT(17) TF_ROT(29) TF_ROT(16) TF_ROT(24)
  x0 += ks1; x1 += ks2 + 4u;
  TF_ROT(13) TF_ROT(15) TF_ROT(26) TF_ROT(6)
  x0 += ks2; x1 += ks0 + 5u;
#undef TF_ROT
}

__global__ __launch_bounds__(256) void idx_kernel(int* __restrict__ idx, unsigned k2a, unsigned k2b,
                                                  int S2, int Lmask){
  int j = blockIdx.x*256 + threadIdx.x;
  if (j >= S2) return;
  unsigned x0 = (unsigned)j, x1 = (unsigned)(S2 + j);
  tf2x32(k2a, k2b, x0, x1);
  idx[j]      = (int)(x0 & (unsigned)Lmask);
  idx[S2 + j] = (int)(x1 & (unsigned)Lmask);
}

// ---------------- positional-embedding table (batch-independent) ----------------
__global__ __launch_bounds__(256) void pe_kernel(float* __restrict__ pe, int L){
  int i = blockIdx.x*256 + threadIdx.x;
  int d = i % DM, l = i / DM;
  const float scale = -0.017988946f;  // -ln(10000)/512
  float freq = expf((float)(d & ~1) * scale);
  float ang  = (float)l * freq;
  pe[i] = (d & 1) ? cosf(ang) : sinf(ang);
}

// ---------------- transpose token-conv weights: tcwT[j][d] = tcw[d][c][kk], j=kk*7+c ----------------
__global__ __launch_bounds__(256) void packtcw(const float* __restrict__ tcw, float* __restrict__ tcwT){
  int i = blockIdx.x*256 + threadIdx.x;
  if (i >= 21*DM) return;
  int j = i / DM, d = i % DM;
  tcwT[(size_t)j*DM + d] = tcw[(size_t)d*21 + (j%7)*3 + (j/7)];
}

// ---------------- token embed: one block per (b,l) row; optional bf16 shadow hb ----------------
__global__ __launch_bounds__(256) void embed2(const float* __restrict__ x, const float* __restrict__ tcwT,
                                              const float* __restrict__ pe, float* __restrict__ h,
                                              unsigned short* __restrict__ hb, int L){
  int row = blockIdx.x; int l = row % L, b = row / L;
  __shared__ float xs[21];
  int t = threadIdx.x;
  if (t < 21){
    int c = t % 7, kk = t / 7;
    int ls = l + kk - 1; ls = (ls < 0) ? ls + L : (ls >= L ? ls - L : ls);
    xs[t] = x[((size_t)b*L + ls)*7 + c];
  }
  __syncthreads();
  for (int d = t; d < DM; d += 256){
    float acc = 0.f;
#pragma unroll
    for (int j=0;j<21;j++) acc += xs[j]*tcwT[j*DM + d];
    float val = acc + pe[(size_t)l*DM + d];
    h[(size_t)row*DM + d] = val;
    if (hb) hb[(size_t)row*DM + d] = f2b(val);
  }
}

// ---------------- fp32 -> bf16 conversion ----------------
__global__ __launch_bounds__(256) void f2b_vec(const float* __restrict__ src, unsigned short* __restrict__ dst, int n4){
  int i = blockIdx.x*256 + threadIdx.x;
  if (i >= n4) return;
  float4 v = ((const float4*)src)[i];
  uint2 o; o.x = cvtpk2(v.x, v.y); o.y = cvtpk2(v.z, v.w);
  ((uint2*)dst)[i] = o;
}

// ---------------- pack conv weights along K: wtapK[n][tap*512+c] = dcw[n][c][tap] ----------------
__global__ __launch_bounds__(256) void packconv(const float* __restrict__ dcw, unsigned short* __restrict__ wtapK){
  int i = blockIdx.x*256 + threadIdx.x;
  if (i >= 3*DM*DM) return;
  int n = i / (3*DM); int rem = i % (3*DM); int tap = rem / DM; int c = rem % DM;
  wtapK[(size_t)n*(3*DM) + tap*DM + c] = f2b(dcw[((size_t)n*DM + c)*3 + tap]);
}

// ---------------- concat qkv bias ----------------
__global__ __launch_bounds__(256) void catb_kernel(const float* __restrict__ a, const float* __restrict__ b,
    const float* __restrict__ c, float* __restrict__ o){
  int i = blockIdx.x*256 + threadIdx.x;
  if (i >= 1536) return;
  o[i] = (i < 512) ? a[i] : (i < 1024 ? b[i-512] : c[i-1024]);
}

// =======================================================================
// bgemm_dp: counted-vmcnt 3-deep pipelined GEMM (T3+T4), bf16 A, TN=64,
// K = NITER*64. LDS ring: 3 stages x (16KB A + 8KB B) = 72KB -> 2 blk/CU.
// Per iter: s_waitcnt vmcnt(12/6/0) -> barrier -> MFMA on slot t%3 ->
// barrier -> issue tile t+3 into slot t%3 (steady state never drains).
// Epilogue: conflict-free LDS-staged coalesced writeback.
// Used for QKV (bf16 shadow A) and w2 (bf16 mid A).
// =======================================================================
template<int NITER>
__global__ __launch_bounds__(256) void bgemm_dp(const unsigned short* __restrict__ A16,
    const unsigned short* __restrict__ Wb, const float* __restrict__ bias, void* __restrict__ C,
    int N, int act, int outbf, int qkv, size_t bufstride, int swz){
  constexpr int TN = 64, NJ = 2, SWM = TN/16 - 1;
  const int K = NITER*64;
  __shared__ unsigned short LDSB[3*12288];    // 3 x 24KB
  int tid = threadIdx.x;
  int w = tid >> 6, ln = tid & 63;

  int bx = blockIdx.x, by = blockIdx.y;
  if (swz){
    int XT = gridDim.x, YT = gridDim.y;
    int lid = by*XT + bx;
    int xcd = lid & 7, s = lid >> 3;
    int ych = YT >> 3;
    int CHv = ych < swz ? ych : swz;
    int yloc = s % CHv;
    int t2 = s / CHv;
    int xx = t2 % XT;
    int chunk = t2 / XT;
    by = xcd*ych + chunk*CHv + yloc;
    bx = xx;
  }
  int row0 = by*128, col0 = bx*TN;

  long aBase[4]; int aCol[4];
#pragma unroll
  for (int g=0; g<4; g++){
    int ch = g*256 + tid;
    int r = ch >> 3, c = ch & 7;
    aCol[g] = (c ^ (r & 7))*8;
    aBase[g] = (long)(row0 + r) * K;
  }
  long bBase[2];
#pragma unroll
  for (int g=0; g<2; g++){
    int ch = g*256 + tid;
    int r = ch >> 3, c = ch & 7;
    bBase[g] = (long)(col0 + r)*K + (c ^ (r & 7))*8;
  }
  int raBase[4], rbBase[2];
#pragma unroll
  for (int i=0;i<4;i++)  raBase[i] = ((w&1)*64 + i*16 + (ln&15))*8;
#pragma unroll
  for (int j=0;j<2;j++)  rbBase[j] = ((w>>1)*32 + j*16 + (ln&15))*8;

  float4v acc[4][NJ] = {};

  auto issue = [&](int t, int slot){
    int k0 = t*64;
    char* sa = (char*)LDSB + slot*24576;
    char* sb = sa + 16384;
#pragma unroll
    for (int g=0; g<4; g++)
      GLL(A16 + aBase[g] + k0 + aCol[g], sa + g*4096 + w*1024);
#pragma unroll
    for (int g=0; g<2; g++)
      GLL(Wb + bBase[g] + k0, sb + g*4096 + w*1024);
  };

  issue(0, 0);
  issue(1, 1);
  issue(2, 2);

  int slot = 0;
  for (int t=0; t<NITER; t++){
    if (t+2 < NITER)      asm volatile("s_waitcnt vmcnt(12)" ::: "memory");
    else if (t+1 < NITER) asm volatile("s_waitcnt vmcnt(6)" ::: "memory");
    else                  asm volatile("s_waitcnt vmcnt(0)" ::: "memory");
    __builtin_amdgcn_s_barrier();
    asm volatile("" ::: "memory");
    const char* ab = (const char*)LDSB + slot*24576;
    const char* bb = ab + 16384;
#pragma unroll
    for (int s=0;s<2;s++){
      int xs = (s*4 + (ln>>4)) ^ (ln&7);
      short8 af[4], bf[NJ];
#pragma unroll
      for (int i=0;i<4;i++)  af[i] = *(const short8*)(ab + (raBase[i] + xs)*16);
#pragma unroll
      for (int j=0;j<NJ;j++) bf[j] = *(const short8*)(bb + (rbBase[j] + xs)*16);
#pragma unroll
      for (int i=0;i<4;i++)
#pragma unroll
        for (int j=0;j<NJ;j++)
          acc[i][j] = __builtin_amdgcn_mfma_f32_16x16x32_bf16(af[i], bf[j], acc[i][j], 0, 0, 0);
    }
    __builtin_amdgcn_s_barrier();
    asm volatile("" ::: "memory");
    if (t+3 < NITER) issue(t+3, slot);
    slot = (slot==2) ? 0 : slot+1;
  }

  float* Cf = (float*)C;
  unsigned short* Cb = (unsigned short*)C;
  if (outbf){
    int clBase = (w>>1)*32 + (ln & 15);
#pragma unroll
    for (int i=0;i<4;i++){
      int rlBase = (w&1)*64 + i*16 + (ln>>4)*4;
      int xr = ((rlBase>>2) & SWM) << 4;
#pragma unroll
      for (int j=0;j<NJ;j++){
        int cl = clBase + j*16;
        int colb = col0 + cl;
        float vv[4];
#pragma unroll
        for (int r=0;r<4;r++){
          float v = acc[i][j][r];
          if (bias) v += bias[colb];
          if (act){
            float z = 0.7978845608f * v * (1.f + 0.044715f*v*v);
            float e = __expf(2.f*z);
            v = v * (1.f - 1.f/(e + 1.f));
          }
          vv[r] = v;
        }
        unsigned p01 = cvtpk2(vv[0], vv[1]);
        unsigned p23 = cvtpk2(vv[2], vv[3]);
        int sc = cl ^ xr;
        LDSB[(rlBase+0)*TN + sc] = (unsigned short)p01;
        LDSB[(rlBase+1)*TN + sc] = (unsigned short)(p01>>16);
        LDSB[(rlBase+2)*TN + sc] = (unsigned short)p23;
        LDSB[(rlBase+3)*TN + sc] = (unsigned short)(p23>>16);
      }
    }
    __syncthreads();
    constexpr int CPR = TN/8;
#pragma unroll
    for (int e = 0; e < 128*CPR; e += 256){
      int idx = e + tid;
      int rl = idx / CPR, c8 = (idx % CPR)*8;
      int sc8 = c8 ^ (((rl>>2) & SWM) << 4);
      uint4 val = *(const uint4*)&LDSB[rl*TN + sc8];
      int grow = row0 + rl;
      int colb = col0 + c8;
      if (qkv){
        int bsel = colb >> 9;
        *(uint4*)&Cb[(size_t)bsel*bufstride + (size_t)grow*512 + (colb & 511)] = val;
      } else {
        *(uint4*)&Cb[(size_t)grow*N + colb] = val;
      }
    }
  } else {
    int colb0 = col0 + (w>>1)*32 + (ln & 15);
#pragma unroll
    for (int i=0;i<4;i++){
      int growb = row0 + (w&1)*64 + i*16 + (ln>>4)*4;
#pragma unroll
      for (int j=0;j<NJ;j++){
        int colb = colb0 + j*16;
#pragma unroll
        for (int r=0;r<4;r++){
          float v = acc[i][j][r];
          if (bias) v += bias[colb];
          if (act){
            float z = 0.7978845608f * v * (1.f + 0.044715f*v*v);
            float e = __expf(2.f*z);
            v = v * (1.f - 1.f/(e + 1.f));
          }
          Cf[(size_t)(growb+r)*N + colb] = v;
        }
      }
    }
  }
}

// =======================================================================
// bgemm2 (R9 form): bf16 MFMA GEMM, 128xTN tile, BK=64, single-buffered
// staging + conflict-free LDS-staged coalesced epilogue.
// Used for QKV fallback (A32), w1 (TN=128) and conv (A32).
// =======================================================================
template<int TN, int A32>
__global__ __launch_bounds__(256) void bgemm2(const void* __restrict__ Ain,
    const unsigned short* __restrict__ Wb, const float* __restrict__ bias, void* __restrict__ C,
    int N, int K, int L, int convmode, int act, int outbf, int qkv, size_t bufstride, int swz){
  constexpr int NJ = TN/32;
  constexpr int BR = TN/32;
  constexpr int SWM = TN/16 - 1;
  __shared__ unsigned short LDSBUF[128*64 + TN*64];
  unsigned short* As = LDSBUF;
  unsigned short* Bs = LDSBUF + 128*64;
  int tid = threadIdx.x;
  int w = tid >> 6, ln = tid & 63;

  int bx = blockIdx.x, by = blockIdx.y;
  if (swz){
    int XT = gridDim.x, YT = gridDim.y;
    int lid = by*XT + bx;
    int xcd = lid & 7, s = lid >> 3;
    int ych = YT >> 3;
    int CHv = ych < swz ? ych : swz;
    int yloc = s % CHv;
    int t2 = s / CHv;
    int xx = t2 % XT;
    int chunk = t2 / XT;
    by = xcd*ych + chunk*CHv + yloc;
    bx = xx;
  }
  int row0 = by*128, col0 = bx*TN;
  int KA = convmode ? 512 : K;

  long aBase[4], dPrev[4], dNext[4]; int aCol[4];
#pragma unroll
  for (int g=0; g<4; g++){
    int ch = g*256 + tid;
    int r = ch >> 3, c = ch & 7;
    int gc = c ^ (r & 7);
    int gr = row0 + r;
    aCol[g] = gc*8;
    aBase[g] = (long)gr * KA;
    if (convmode){
      int l = gr % L;
      dPrev[g] = (l==0)   ? (long)(L-1)*KA : -(long)KA;
      dNext[g] = (l==L-1) ? -(long)(L-1)*KA : (long)KA;
    } else { dPrev[g]=0; dNext[g]=0; }
  }
  long bBase[BR];
#pragma unroll
  for (int g=0; g<BR; g++){
    int ch = g*256 + tid;
    int r = ch >> 3, c = ch & 7;
    int gc = c ^ (r & 7);
    bBase[g] = (long)(col0 + r)*K + gc*8;
  }
  int raBase[4], rbBase[NJ];
#pragma unroll
  for (int i=0;i<4;i++)  raBase[i] = ((w&1)*64 + i*16 + (ln&15))*8;
#pragma unroll
  for (int j=0;j<NJ;j++) rbBase[j] = ((w>>1)*(TN/2) + j*16 + (ln&15))*8;

  float4v acc[4][NJ] = {};
  int nIter = K/64;
  const unsigned short* A16 = (const unsigned short*)Ain;
  const float* Af = (const float*)Ain;

  for (int it=0; it<nIter; it++){
    int k0 = it*64;
    int kk = convmode ? (k0 & 511) : k0;
    int seg = convmode ? (k0 >> 9) : 1;
    if (A32){
#pragma unroll
      for (int g=0; g<4; g++){
        long d = convmode ? ((seg==0) ? dPrev[g] : (seg==2 ? dNext[g] : 0)) : 0;
        const float* src = Af + aBase[g] + d + kk + aCol[g];
        float4 v0 = *(const float4*)src;
        float4 v1 = *(const float4*)(src+4);
        uint4 pk;
        pk.x = cvtpk2(v0.x, v0.y); pk.y = cvtpk2(v0.z, v0.w);
        pk.z = cvtpk2(v1.x, v1.y); pk.w = cvtpk2(v1.z, v1.w);
        *(uint4*)((char*)As + g*4096 + tid*16) = pk;
      }
    } else {
#pragma unroll
      for (int g=0; g<4; g++){
        long d = convmode ? ((seg==0) ? dPrev[g] : (seg==2 ? dNext[g] : 0)) : 0;
        GLL(A16 + aBase[g] + d + kk + aCol[g], (char*)As + g*4096 + w*1024);
      }
    }
#pragma unroll
    for (int g=0; g<BR; g++)
      GLL(Wb + bBase[g] + k0, (char*)Bs + g*4096 + w*1024);
    __syncthreads();
    const char* ab = (const char*)As;
    const char* bb = (const char*)Bs;
#pragma unroll
    for (int s=0;s<2;s++){
      int xs = (s*4 + (ln>>4)) ^ (ln&7);
      short8 af[4], bf[NJ];
#pragma unroll
      for (int i=0;i<4;i++)  af[i] = *(const short8*)(ab + (raBase[i] + xs)*16);
#pragma unroll
      for (int j=0;j<NJ;j++) bf[j] = *(const short8*)(bb + (rbBase[j] + xs)*16);
#pragma unroll
      for (int i=0;i<4;i++)
#pragma unroll
        for (int j=0;j<NJ;j++)
          acc[i][j] = __builtin_amdgcn_mfma_f32_16x16x32_bf16(af[i], bf[j], acc[i][j], 0, 0, 0);
    }
    __syncthreads();
  }

  float* Cf = (float*)C;
  unsigned short* Cb = (unsigned short*)C;
  if (outbf){
    int clBase = (w>>1)*(TN/2) + (ln & 15);
#pragma unroll
    for (int i=0;i<4;i++){
      int rlBase = (w&1)*64 + i*16 + (ln>>4)*4;
      int xr = ((rlBase>>2) & SWM) << 4;
#pragma unroll
      for (int j=0;j<NJ;j++){
        int cl = clBase + j*16;
        int colb = col0 + cl;
        float vv[4];
#pragma unroll
        for (int r=0;r<4;r++){
          float v = acc[i][j][r];
          if (bias) v += bias[colb];
          if (act){
            float z = 0.7978845608f * v * (1.f + 0.044715f*v*v);
            float e = __expf(2.f*z);
            v = v * (1.f - 1.f/(e + 1.f));
          }
          vv[r] = v;
        }
        unsigned p01 = cvtpk2(vv[0], vv[1]);
        unsigned p23 = cvtpk2(vv[2], vv[3]);
        int sc = cl ^ xr;
        LDSBUF[(rlBase+0)*TN + sc] = (unsigned short)p01;
        LDSBUF[(rlBase+1)*TN + sc] = (unsigned short)(p01>>16);
        LDSBUF[(rlBase+2)*TN + sc] = (unsigned short)p23;
        LDSBUF[(rlBase+3)*TN + sc] = (unsigned short)(p23>>16);
      }
    }
    __syncthreads();
    constexpr int CPR = TN/8;
#pragma unroll
    for (int e = 0; e < 128*CPR; e += 256){
      int idx = e + tid;
      int rl = idx / CPR, c8 = (idx % CPR)*8;
      int sc8 = c8 ^ (((rl>>2) & SWM) << 4);
      uint4 val = *(const uint4*)&LDSBUF[rl*TN + sc8];
      int grow = row0 + rl;
      int colb = col0 + c8;
      if (qkv){
        int bsel = colb >> 9;
        *(uint4*)&Cb[(size_t)bsel*bufstride + (size_t)grow*512 + (colb & 511)] = val;
      } else {
        *(uint4*)&Cb[(size_t)grow*N + colb] = val;
      }
    }
  } else {
    int colb0 = col0 + (w>>1)*(TN/2) + (ln & 15);
#pragma unroll
    for (int i=0;i<4;i++){
      int growb = row0 + (w&1)*64 + i*16 + (ln>>4)*4;
#pragma unroll
      for (int j=0;j<NJ;j++){
        int colb = colb0 + j*16;
#pragma unroll
        for (int r=0;r<4;r++){
          float v = acc[i][j][r];
          if (bias) v += bias[colb];
          if (act){
            float z = 0.7978845608f * v * (1.f + 0.044715f*v*v);
            float e = __expf(2.f*z);
            v = v * (1.f - 1.f/(e + 1.f));
          }
          Cf[(size_t)(growb+r)*N + colb] = v;
        }
      }
    }
  }
}

// ---------------- sample_m2: one wave per (b,l), all 8 heads; 16B/lane loads ----------------
__global__ __launch_bounds__(256) void sample_m2(const unsigned short* __restrict__ q,
    const unsigned short* __restrict__ k, const int* __restrict__ idx, float* __restrict__ m, int L, int u){
  int w = (blockIdx.x*256 + threadIdx.x) >> 6;
  int lane = threadIdx.x & 63;
  int l = w % L; int b = w / L;
  const unsigned short* qrow = q + (size_t)w*DM + lane*8;
  uint4 qq = *(const uint4*)qrow;
  float qv[8];
  qv[0]=b2f((unsigned short)(qq.x&0xffff)); qv[1]=b2f((unsigned short)(qq.x>>16));
  qv[2]=b2f((unsigned short)(qq.y&0xffff)); qv[3]=b2f((unsigned short)(qq.y>>16));
  qv[4]=b2f((unsigned short)(qq.z&0xffff)); qv[5]=b2f((unsigned short)(qq.z>>16));
  qv[6]=b2f((unsigned short)(qq.w&0xffff)); qv[7]=b2f((unsigned short)(qq.w>>16));
  const unsigned short* kb = k + (size_t)b*L*DM + lane*8;
  const int* ip = idx + (size_t)l*u;
  float mx = -1e30f, sum = 0.f;
  for (int s=0; s<u; s++){
    int kp = ip[s];
    uint4 kk = *(const uint4*)(kb + (size_t)kp*DM);
    float p;
    p  = qv[0]*b2f((unsigned short)(kk.x&0xffff)) + qv[1]*b2f((unsigned short)(kk.x>>16));
    p += qv[2]*b2f((unsigned short)(kk.y&0xffff)) + qv[3]*b2f((unsigned short)(kk.y>>16));
    p += qv[4]*b2f((unsigned short)(kk.z&0xffff)) + qv[5]*b2f((unsigned short)(kk.z>>16));
    p += qv[6]*b2f((unsigned short)(kk.w&0xffff)) + qv[7]*b2f((unsigned short)(kk.w>>16));
    p += __shfl_xor(p, 1); p += __shfl_xor(p, 2); p += __shfl_xor(p, 4);
    mx = fmaxf(mx, p); sum += p;
  }
  if ((lane & 7) == 0){
    int hh = lane >> 3;
    m[((size_t)b*8 + hh)*L + l] = mx - sum/(float)u;
  }
}

// ---------------- iterative top-u argmax per (b,h): register-resident, wave-shuffle reduce ----------------
template<int NS>
__global__ __launch_bounds__(256) void topk_kernel(const float* __restrict__ m, int* __restrict__ top, int L, int u){
  int bh = blockIdx.x;
  const float* mm = m + (size_t)bh*L;
  int t = threadIdx.x;
  float v[NS];
#pragma unroll
  for (int s=0; s<NS; s++) v[s] = mm[s*256 + t];
  __shared__ float rv[4];
  __shared__ int   ri[4];
  for (int it=0; it<u; it++){
    float bv = -1e30f; int bi = 0x7fffffff;
#pragma unroll
    for (int s=0; s<NS; s++){
      float x = v[s]; int i = s*256 + t;
      if (x > bv || (x == bv && i < bi)) { bv = x; bi = i; }
    }
#pragma unroll
    for (int off=32; off; off>>=1){
      float ov = __shfl_xor(bv, off); int oi = __shfl_xor(bi, off);
      if (ov > bv || (ov == bv && oi < bi)) { bv = ov; bi = oi; }
    }
    if ((t & 63) == 0){ rv[t>>6] = bv; ri[t>>6] = bi; }
    __syncthreads();
    bv = rv[0]; bi = ri[0];
#pragma unroll
    for (int k2=1; k2<4; k2++){
      float ov = rv[k2]; int oi = ri[k2];
      if (ov > bv || (ov == bv && oi < bi)) { bv = ov; bi = oi; }
    }
    if (t == 0) top[bh*u + it] = bi;
    if ((bi & 255) == t){
      int slot = bi >> 8;
#pragma unroll
      for (int s=0; s<NS; s++) if (s == slot) v[s] = -1e31f;
    }
    __syncthreads();
  }
}

// ---------------- column mean, two-stage ----------------
#define CMC 32
__global__ __launch_bounds__(256) void colmean1(const float* __restrict__ src, float* __restrict__ part, int L){
  int b = blockIdx.x, ch = blockIdx.y;
  int rpb = L / CMC;
  int t = threadIdx.x;
  const float* p = src + ((size_t)b*L + (size_t)ch*rpb)*DM;
  float s0 = 0.f, s1 = 0.f;
  for (int r=0; r<rpb; r++){ s0 += p[(size_t)r*DM + t]; s1 += p[(size_t)r*DM + t + 256]; }
  float* o = part + ((size_t)b*CMC + ch)*DM;
  o[t] = s0; o[t+256] = s1;
}
__global__ __launch_bounds__(256) void colmean2(const float* __restrict__ part, float* __restrict__ dst, int L){
  int i = blockIdx.x*256 + threadIdx.x;
  int d = i % DM, b = i / DM;
  float s = 0.f;
  for (int c=0; c<CMC; c++) s += part[((size_t)b*CMC + c)*DM + d];
  dst[i] = s / (float)L;
}

// ---------------- tiny fp32 GEMM: one block per row ----------------
__global__ __launch_bounds__(256) void tiny_gemm(const float* __restrict__ A, const float* __restrict__ W,
    const float* __restrict__ bias, float* __restrict__ C, int N, int K){
  int row = blockIdx.x;
  const float* ar = A + (size_t)row*K;
  __shared__ float as[DM];
  for (int k=threadIdx.x; k<K; k+=256) as[k] = ar[k];
  __syncthreads();
  for (int n = threadIdx.x; n < N; n += 256){
    float acc = bias ? bias[n] : 0.f;
    const float* wr = W + (size_t)n*K;
    for (int k=0; k<K; k++) acc += as[k]*wr[k];
    C[(size_t)row*N + n] = acc;
  }
}

// ---------------- gather q rows for top queries (bf16 q -> fp32 qred) ----------------
__global__ __launch_bounds__(256) void qred_kernel(const unsigned short* __restrict__ q, const int* __restrict__ top,
    float* __restrict__ qred, int L, int u, int n){
  int i = blockIdx.x*256 + threadIdx.x;
  if (i >= n) return;
  int d = i & 63; int rest = i >> 6; int j = rest % u; int bh = rest / u;
  int hh = bh & 7; int b = bh >> 3;
  int pos = top[bh*u + j];
  qred[i] = b2f(q[((size_t)b*L + pos)*DM + hh*DH + d]);
}

// =======================================================================
// flash_attn: fused QK^T -> online softmax -> PV, key-split partials.
// =======================================================================
#define FKT 128
__global__ __launch_bounds__(256) void flash_attn(const float* __restrict__ qred,
    const unsigned short* __restrict__ kbuf, const unsigned short* __restrict__ vbuf,
    float* __restrict__ partM, float* __restrict__ partL, float* __restrict__ partA,
    int L, int u, int KS){
  int ks = blockIdx.x, bh = blockIdx.y; int b = bh >> 3, h = bh & 7;
  int t = threadIdx.x;
  __shared__ float Qs[38*64];              // 9.7 KB
  __shared__ unsigned short Ks[FKT*64];    // 16 KB (xor-swizzled chunks)
  __shared__ unsigned short Vs[FKT*64];    // 16 KB (natural)
  __shared__ float Ss[38*FKT];             // 19.4 KB
  for (int i=t;i<u*64;i+=256) Qs[i] = qred[(size_t)bh*u*64 + i];
  int lane = t & 63, w = t >> 6;
  float rm[10], rl[10], racc[10];
#pragma unroll
  for (int j=0;j<10;j++){ rm[j]=-1e30f; rl[j]=0.f; racc[j]=0.f; }
  int nk = L / KS;
  int kbase = ks*nk;
  int key = t & 127, rh = t >> 7;
  for (int kt = 0; kt < nk; kt += FKT){
    __syncthreads();
    for (int e = t; e < FKT*8; e += 256){   // chunk id: k=e>>3, c=e&7 (16B chunks)
      int k = e >> 3, c = e & 7;
      size_t gidx = ((size_t)(b*L + kbase + kt + k))*DM + h*DH + c*8;
      *(uint4*)((char*)Ks + (size_t)(k*8 + (c ^ (k&7)))*16) = *(const uint4*)(kbuf + gidx);
      *(uint4*)((char*)Vs + (size_t)e*16) = *(const uint4*)(vbuf + gidx);
    }
    __syncthreads();
    // scores: thread (key, rh) computes rows rh, rh+2, ...
    for (int r = rh; r < u; r += 2){
      const float4* q4 = (const float4*)(Qs + r*64);
      float acc = 0.f;
#pragma unroll
      for (int c=0;c<8;c++){
        short8 kk = *(const short8*)((char*)Ks + (size_t)(key*8 + (c ^ (key&7)))*16);
        float4 qa = q4[c*2], qb = q4[c*2+1];
        acc += qa.x*b2f((unsigned short)kk[0]) + qa.y*b2f((unsigned short)kk[1])
             + qa.z*b2f((unsigned short)kk[2]) + qa.w*b2f((unsigned short)kk[3]);
        acc += qb.x*b2f((unsigned short)kk[4]) + qb.y*b2f((unsigned short)kk[5])
             + qb.z*b2f((unsigned short)kk[6]) + qb.w*b2f((unsigned short)kk[7]);
      }
      Ss[r*FKT + key] = acc * 0.125f;
    }
    __syncthreads();
    // online softmax + PV: wave w owns rows w, w+4, ... (lane = output dim)
    int j = 0;
    for (int r = w; r < u; r += 4, j++){
      float s0 = Ss[r*FKT + lane], s1 = Ss[r*FKT + 64 + lane];
      float mx = fmaxf(s0, s1);
#pragma unroll
      for (int off=32; off; off>>=1) mx = fmaxf(mx, __shfl_xor(mx, off));
      float newm = fmaxf(rm[j], mx);
      float scale = expf(rm[j] - newm);
      float p0 = expf(s0 - newm), p1 = expf(s1 - newm);
      float ps = p0 + p1;
#pragma unroll
      for (int off=32; off; off>>=1) ps += __shfl_xor(ps, off);
      rl[j] = rl[j]*scale + ps;
      rm[j] = newm;
      Ss[r*FKT + lane] = p0; Ss[r*FKT + 64 + lane] = p1;
      float a = racc[j]*scale;
      for (int k=0;k<FKT;k+=4){
        float pa = Ss[r*FKT+k], pb = Ss[r*FKT+k+1], pc = Ss[r*FKT+k+2], pd = Ss[r*FKT+k+3];
        a += pa*b2f(Vs[(k+0)*64+lane]) + pb*b2f(Vs[(k+1)*64+lane])
           + pc*b2f(Vs[(k+2)*64+lane]) + pd*b2f(Vs[(k+3)*64+lane]);
      }
      racc[j] = a;
    }
  }
  int j = 0;
  for (int r = w; r < u; r += 4, j++){
    size_t base = ((size_t)bh*KS + ks)*u + r;
    if (lane == 0){ partM[base] = rm[j]; partL[base] = rl[j]; }
    partA[base*64 + lane] = racc[j];
  }
}

// ---------------- merge key-split partials -> ctxt ----------------
__global__ __launch_bounds__(256) void flash_merge(const float* __restrict__ partM, const float* __restrict__ partL,
    const float* __restrict__ partA, float* __restrict__ ctxt, int u, int KS, int n){
  int i = blockIdx.x*256 + threadIdx.x;
  if (i >= n) return;
  int nn = i & 63; int rest = i >> 6; int r = rest % u; int bhl = rest / u;
  size_t base0 = ((size_t)bhl*KS)*u + r;
  float gm = -1e30f;
  for (int s=0;s<KS;s++) gm = fmaxf(gm, partM[base0 + (size_t)s*u]);
  float lt = 0.f, at = 0.f;
  for (int s=0;s<KS;s++){
    float e = expf(partM[base0 + (size_t)s*u] - gm);
    lt += partL[base0 + (size_t)s*u]*e;
    at += partA[(base0 + (size_t)s*u)*64 + nn]*e;
  }
  ctxt[i] = at / lt;
}

// ---------------- sparse correction: h[b,pos] += (ctxt - vmean_slice)@wo_slice^T ----------------
__global__ __launch_bounds__(256) void scatter_delta(const float* __restrict__ ctxt, const float* __restrict__ vmean,
    const float* __restrict__ wo, const int* __restrict__ top, float* __restrict__ h, int L, int u){
  int bid = blockIdx.x;
  int j = bid % u; int bh = bid / u; int hh = bh & 7; int b = bh >> 3;
  int pos = top[bh*u + j];
  __shared__ float delta[DH];
  int t = threadIdx.x;
  if (t < DH) delta[t] = ctxt[(size_t)(bh*u + j)*DH + t] - vmean[b*DM + hh*DH + t];
  __syncthreads();
  float* hrow = h + ((size_t)b*L + pos)*DM;
  const float* wbase = wo + hh*DH;
  for (int n = t; n < DM; n += 256){
    float acc = 0.f;
    const float* wr = wbase + (size_t)n*DM;
#pragma unroll
    for (int dd=0; dd<DH; dd++) acc += delta[dd] * wr[dd];
    atomicAdd(&hrow[n], acc);
  }
}

// ---------------- LayerNorm D=512, wave-per-row (4 rows/block, no barriers) ----------------
__global__ __launch_bounds__(256) void ln_kernel(const float* __restrict__ X, const void* __restrict__ Yadd,
    int yb, const float* __restrict__ g, const float* __restrict__ bta, void* __restrict__ Out, int ob,
    const float* __restrict__ cwv, int Lrow, int row0g){
  int w = threadIdx.x >> 6, lane = threadIdx.x & 63;
  size_t row = (size_t)blockIdx.x*4 + w;
  int d0 = lane*8;
  const float* xr = X + row*DM + d0;
  float4 a = *(const float4*)xr;
  float4 b = *(const float4*)(xr+4);
  float v[8] = {a.x,a.y,a.z,a.w,b.x,b.y,b.z,b.w};
  if (cwv){
    int bb = (int)(((size_t)row0g + row) / (size_t)Lrow);
    const float* cp = cwv + (size_t)bb*DM + d0;
    float4 c0 = *(const float4*)cp, c1 = *(const float4*)(cp+4);
    v[0]+=c0.x; v[1]+=c0.y; v[2]+=c0.z; v[3]+=c0.w;
    v[4]+=c1.x; v[5]+=c1.y; v[6]+=c1.z; v[7]+=c1.w;
  }
  if (Yadd){
    if (yb){
      const unsigned short* yr = (const unsigned short*)Yadd + row*DM + d0;
      uint4 yv = *(const uint4*)yr;
      v[0]+=b2f((unsigned short)(yv.x&0xffff)); v[1]+=b2f((unsigned short)(yv.x>>16));
      v[2]+=b2f((unsigned short)(yv.y&0xffff)); v[3]+=b2f((unsigned short)(yv.y>>16));
      v[4]+=b2f((unsigned short)(yv.z&0xffff)); v[5]+=b2f((unsigned short)(yv.z>>16));
      v[6]+=b2f((unsigned short)(yv.w&0xffff)); v[7]+=b2f((unsigned short)(yv.w>>16));
    } else {
      const float* yr = (const float*)Yadd + row*DM + d0;
      float4 y0 = *(const float4*)yr, y1 = *(const float4*)(yr+4);
      v[0]+=y0.x; v[1]+=y0.y; v[2]+=y0.z; v[3]+=y0.w;
      v[4]+=y1.x; v[5]+=y1.y; v[6]+=y1.z; v[7]+=y1.w;
    }
  }
  float s = 0.f, q = 0.f;
#pragma unroll
  for (int i=0;i<8;i++){ s += v[i]; q += v[i]*v[i]; }
#pragma unroll
  for (int off=32; off; off>>=1){ s += __shfl_xor(s,off); q += __shfl_xor(q,off); }
  float mu  = s * (1.0f/DM);
  float var = q * (1.0f/DM) - mu*mu;
  float r = rsqrtf(var + 1e-5f);
  const float* gp = g + d0; const float* bp = bta + d0;
  float4 g0 = *(const float4*)gp, g1 = *(const float4*)(gp+4);
  float4 b0 = *(const float4*)bp, b1 = *(const float4*)(bp+4);
  float gg[8] = {g0.x,g0.y,g0.z,g0.w,g1.x,g1.y,g1.z,g1.w};
  float bb2[8] = {b0.x,b0.y,b0.z,b0.w,b1.x,b1.y,b1.z,b1.w};
  float o[8];
#pragma unroll
  for (int i=0;i<8;i++) o[i] = (v[i]-mu)*r*gg[i] + bb2[i];
  if (ob){
    uint4 pk;
    pk.x = cvtpk2(o[0],o[1]); pk.y = cvtpk2(o[2],o[3]);
    pk.z = cvtpk2(o[4],o[5]); pk.w = cvtpk2(o[6],o[7]);
    *(uint4*)((unsigned short*)Out + row*DM + d0) = pk;
  } else {
    float* Of = (float*)Out + row*DM + d0;
    *(float4*)Of     = make_float4(o[0],o[1],o[2],o[3]);
    *(float4*)(Of+4) = make_float4(o[4],o[5],o[6],o[7]);
  }
}

// ---------------- BN partial sums over bf16 conv output (grid: 8 x 128) ----------------
__global__ __launch_bounds__(256) void bnstat1(const unsigned short* __restrict__ C, float* __restrict__ partS,
                                               float* __restrict__ partQ, int rpb){
  int chb = blockIdx.x;
  int mb  = blockIdx.y;
  int g = threadIdx.x >> 6, c = threadIdx.x & 63;
  int ch = chb*64 + c;
  float s = 0.f, q = 0.f;
  int r0 = mb * rpb;
  for (int r = r0 + g; r < r0 + rpb; r += 4){
    float v = b2f(C[(size_t)r*DM + ch]); s += v; q += v*v;
  }
  __shared__ float ls[4][64], lq[4][64];
  ls[g][c] = s; lq[g][c] = q;
  __syncthreads();
  if (g == 0){
    s = ls[0][c]+ls[1][c]+ls[2][c]+ls[3][c];
    q = lq[0][c]+lq[1][c]+lq[2][c]+lq[3][c];
    partS[(size_t)mb*DM + ch] = s;
    partQ[(size_t)mb*DM + ch] = q;
  }
}
__global__ __launch_bounds__(256) void bnstat2(const float* __restrict__ partS, const float* __restrict__ partQ,
                                               float* __restrict__ stats, int NB, int M){
  int ch = blockIdx.x*256 + threadIdx.x;
  if (ch >= DM) return;
  float s = 0.f, q = 0.f;
  for (int mb=0; mb<NB; mb++){
    s += partS[(size_t)mb*DM + ch];
    q += partQ[(size_t)mb*DM + ch];
  }
  float mu = s / (float)M;
  stats[ch] = mu;
  stats[DM + ch] = q / (float)M - mu*mu;
}

// ---------------- BN + ELU + maxpool(3,2); optional bf16 shadow hb ----------------
__global__ __launch_bounds__(256) void bnpool(const unsigned short* __restrict__ C, const float* __restrict__ stats,
    const float* __restrict__ g, const float* __restrict__ bta, float* __restrict__ Out,
    unsigned short* __restrict__ hb, int L, int Lo){
  size_t i = (size_t)blockIdx.x*256 + threadIdx.x;
  int ch = (int)(i % DM);
  size_t r = i / DM;
  int lo = (int)(r % Lo);
  int b  = (int)(r / Lo);
  float mu = stats[ch];
  float rstd = rsqrtf(stats[DM+ch] + 1e-5f);
  float gg = g[ch], bb = bta[ch];
  float best = -1e30f;
#pragma unroll
  for (int t=-1; t<=1; t++){
    int li = 2*lo + t;
    if (li >= 0 && li < L){
      float v = (b2f(C[((size_t)b*L + li)*DM + ch]) - mu)*rstd*gg + bb;
      v = v > 0.f ? v : expm1f(v);
      best = fmaxf(best, v);
    }
  }
  size_t oidx = ((size_t)b*Lo + lo)*DM + ch;
  Out[oidx] = best;
  if (hb) hb[oidx] = f2b(best);
}

// ---------------- final: LN(last row) @ proj^T + proj_b + skip ----------------
__global__ __launch_bounds__(128) void final_kernel(const float* __restrict__ h, const float* __restrict__ x,
    const float* __restrict__ fg, const float* __restrict__ fb, const float* __restrict__ pw,
    const float* __restrict__ pb, const float* __restrict__ sw, const float* __restrict__ sb,
    float* __restrict__ out, int Lf, int L0){
  int b = blockIdx.x;
  const float* row = h + ((size_t)b*Lf + (Lf-1))*DM;
  __shared__ float xn[DM];
  __shared__ float rs[2], rq[2];
  int t = threadIdx.x;
  float v[4]; float s = 0.f, q = 0.f;
#pragma unroll
  for (int i=0;i<4;i++){ v[i] = row[t + i*128]; s += v[i]; q += v[i]*v[i]; }
#pragma unroll
  for (int off=32; off; off>>=1){ s += __shfl_xor(s,off); q += __shfl_xor(q,off); }
  if ((t & 63) == 0){ rs[t>>6] = s; rq[t>>6] = q; }
  __syncthreads();
  s = rs[0]+rs[1]; q = rq[0]+rq[1];
  float mu = s*(1.0f/DM), var = q*(1.0f/DM) - mu*mu;
  float r = rsqrtf(var + 1e-5f);
#pragma unroll
  for (int i=0;i<4;i++){ int d = t + i*128; xn[d] = (v[i]-mu)*r*fg[d] + fb[d]; }
  __syncthreads();
  if (t < 96){
    float acc = pb[t] + sb[t];
    const float* xr = x + ((size_t)b*L0 + (L0-1))*7;
#pragma unroll
    for (int c=0;c<7;c++) acc += xr[c]*sw[t*7+c];
    for (int d=0; d<DM; d++) acc += xn[d]*pw[(size_t)t*DM + d];
    out[b*96 + t] = acc;
  }
}

// =======================================================================
extern "C" void kernel_launch(void* const* d_in, const int* in_sizes, int n_in,
                              void* d_out, int out_size, void* d_ws, size_t ws_size,
                              hipStream_t stream){
  const float* x    = (const float*)d_in[0];
  const float* skw  = (const float*)d_in[1];
  const float* skb  = (const float*)d_in[2];
  const float* tcw  = (const float*)d_in[3];
  const float* wq   = (const float*)d_in[4];
  const float* bq   = (const float*)d_in[5];
  const float* wk   = (const float*)d_in[6];
  const float* bk   = (const float*)d_in[7];
  const float* wv   = (const float*)d_in[8];
  const float* bv   = (const float*)d_in[9];
  const float* wo   = (const float*)d_in[10];
  const float* bo   = (const float*)d_in[11];
  const float* w1   = (const float*)d_in[12];
  const float* b1   = (const float*)d_in[13];
  const float* w2   = (const float*)d_in[14];
  const float* b2   = (const float*)d_in[15];
  const float* ln1g = (const float*)d_in[16];
  const float* ln1b = (const float*)d_in[17];
  const float* ln2g = (const float*)d_in[18];
  const float* ln2b = (const float*)d_in[19];
  const float* dcw  = (const float*)d_in[20];
  const float* dcb  = (const float*)d_in[21];
  const float* bng  = (const float*)d_in[22];
  const float* bnb  = (const float*)d_in[23];
  const float* flg  = (const float*)d_in[24];
  const float* flb  = (const float*)d_in[25];
  const float* pw   = (const float*)d_in[26];
  const float* pb   = (const float*)d_in[27];

  const int B = 32, L0 = 2048, DFF = 2048;
  const int RG = 16384;
  const int RF = 8192;
  char* ws = (char*)d_ws;
  const size_t SZH  = (size_t)B*L0*DM*sizeof(float);
  const size_t SLOT = (size_t)RG*DM*sizeof(unsigned short);

  const size_t WBSZ = (size_t)(3*DM*DM + 2*DFF*DM + 3*DM*DM)*2;
  size_t small_bytes = (size_t)L0*40*4
                     + (size_t)RG*8*4
                     + (size_t)B*8*40*4
                     + (size_t)32*8*40*64*4
                     + (size_t)32*8*40*64*4
                     + 3*(size_t)B*DM*4
                     + 2*(size_t)128*DM*4
                     + (size_t)2*DM*4
                     + (size_t)1536*4
                     + (size_t)B*CMC*DM*4
                     + (size_t)L0*DM*4
                     + (size_t)21*DM*4;
  size_t base_bytes = SZH + 4*SLOT + WBSZ + small_bytes;
  if (ws_size < base_bytes) return;
  // optional bf16 shadow of h (64 MB): enables pipelined QKV without pre-convert
  size_t hb_off = (base_bytes + 255) & ~(size_t)255;
  size_t HBSZ = (size_t)B*L0*DM*2;
  int has_hb = (ws_size >= hb_off + HBSZ) ? 1 : 0;
  unsigned short* hb = has_hb ? (unsigned short*)(ws + hb_off) : nullptr;

  float*          h   = (float*)(ws);
  unsigned short* P0  = (unsigned short*)(ws + SZH);
  unsigned short* P1  = (unsigned short*)(ws + SZH + SLOT);
  unsigned short* P2  = (unsigned short*)(ws + SZH + 2*SLOT);
  unsigned short* P3  = (unsigned short*)(ws + SZH + 3*SLOT);
  unsigned short* wb  = (unsigned short*)(ws + SZH + 4*SLOT);
  unsigned short* wqb = wb;
  unsigned short* w1b = wqb + (size_t)3*DM*DM;
  unsigned short* w2b = w1b + (size_t)DFF*DM;
  unsigned short* wtapK= w2b + (size_t)DM*DFF;
  char* sm = ws + SZH + 4*SLOT + WBSZ;
  int*   idx_buf  = (int*)sm;
  float* m_buf    = (float*)(sm + (size_t)L0*40*4);
  int*   top_all  = (int*)((char*)m_buf + (size_t)RG*8*4);
  float* qred_loc = (float*)((char*)top_all + (size_t)B*8*40*4);
  float* ctxt_all = qred_loc + (size_t)32*8*40*64;
  float* hm       = ctxt_all + (size_t)32*8*40*64;
  float* vmean    = hm + (size_t)B*DM;
  float* cw       = vmean + (size_t)B*DM;
  float* partS    = cw + (size_t)B*DM;
  float* partQ    = partS + (size_t)128*DM;
  float* stats    = partQ + (size_t)128*DM;
  float* bqkv     = stats + (size_t)2*DM;
  float* partC    = bqkv + (size_t)1536;
  float* pe_buf   = partC + (size_t)B*CMC*DM;
  float* tcwT     = pe_buf + (size_t)L0*DM;

  // flash partials live in P0 (free during attention)
  float* fpM = (float*)P0;                       // 256*40
  float* fpL = fpM + (size_t)256*40;             // 256*40
  float* fpA = fpL + (size_t)256*40;             // 256*40*64 (~2.6 MB)

  auto conv_b = [&](const float* src, unsigned short* dst, size_t n){
    f2b_vec<<<(int)((n/4 + 255)/256), 256, 0, stream>>>(src, dst, (int)(n/4));
  };

  pe_kernel<<<(int)(((size_t)L0*DM)/256), 256, 0, stream>>>(pe_buf, L0);
  packtcw<<<(21*DM + 255)/256, 256, 0, stream>>>(tcw, tcwT);
  embed2<<<B*L0, 256, 0, stream>>>(x, tcwT, pe_buf, h, hb, L0);

  int L = L0;
  for (int layer = 0; layer < 3; layer++){
    int M = B * L;
    int u = (int)(5.0 * log((double)L + 1.0));   // 38 / 34 / 31
    int G = RG / L;
    int nG = M / RG;
    int KS = L / 512;                            // 4 / 2 / 1 key-splits
    const float* wv_i = wv + (size_t)layer*DM*DM;  const float* bv_i = bv + (size_t)layer*DM;
    const float* wo_i = wo + (size_t)layer*DM*DM;  const float* bo_i = bo + (size_t)layer*DM;
    const float* b1_i = b1 + (size_t)layer*DFF;
    const float* b2_i = b2 + (size_t)layer*DM;

    conv_b(wq + (size_t)layer*DM*DM, wqb,                    (size_t)DM*DM);
    conv_b(wk + (size_t)layer*DM*DM, wqb + (size_t)DM*DM,    (size_t)DM*DM);
    conv_b(wv_i,                     wqb + (size_t)2*DM*DM,  (size_t)DM*DM);
    conv_b(w1 + (size_t)layer*DFF*DM, w1b, (size_t)DFF*DM);
    conv_b(w2 + (size_t)layer*DM*DFF, w2b, (size_t)DM*DFF);
    catb_kernel<<<6, 256, 0, stream>>>(bq + (size_t)layer*DM, bk + (size_t)layer*DM, bv_i, bqkv);
    if (layer < 2)
      packconv<<<(3*DM*DM + 255)/256, 256, 0, stream>>>(dcw + (size_t)layer*DM*DM*3, wtapK);

    unsigned ka = 0u, kb2 = (unsigned)layer;
    tf2x32(0u, 42u, ka, kb2);
    unsigned a0 = 0u, a1 = 2u;  tf2x32(ka, kb2, a0, a1);
    unsigned c0 = 1u, c1 = 3u;  tf2x32(ka, kb2, c0, c1);
    int S2 = L * u / 2;
    idx_kernel<<<(S2 + 255)/256, 256, 0, stream>>>(idx_buf, a1, c1, S2, L-1);

    for (int g = 0; g < nG; g++){
      const float* hg = h + (size_t)g*RG*DM;
      if (has_hb){
        bgemm_dp<8><<<dim3(24, RG/128), 256, 0, stream>>>(hb + (size_t)g*RG*DM, wqb, bqkv, P1,
            1536, 0, 1, 1, (size_t)RG*DM, 16);
      } else {
        bgemm2<128,1><<<dim3(12, RG/128), 256, 0, stream>>>(hg, wqb, bqkv, P1,
            1536, 512, L, 0, 0, 1, 1, (size_t)RG*DM, 16);
      }
      sample_m2<<<RG/4, 256, 0, stream>>>(P1, P2, idx_buf, m_buf, L, u);
      int* top_g = top_all + (size_t)g*G*8*u;
      if (L == 2048)      topk_kernel<8><<<G*8, 256, 0, stream>>>(m_buf, top_g, L, u);
      else if (L == 1024) topk_kernel<4><<<G*8, 256, 0, stream>>>(m_buf, top_g, L, u);
      else                topk_kernel<2><<<G*8, 256, 0, stream>>>(m_buf, top_g, L, u);
      int nqr = G*8*u*DH;
      qred_kernel<<<(nqr + 255)/256, 256, 0, stream>>>(P1, top_g, qred_loc, L, u, nqr);

      flash_attn<<<dim3(KS, G*8), 256, 0, stream>>>(qred_loc, P2, P3, fpM, fpL, fpA, L, u, KS);
      int nmg = G*8*u*64;
      flash_merge<<<(nmg + 255)/256, 256, 0, stream>>>(fpM, fpL, fpA,
          ctxt_all + (size_t)g*G*8*u*64, u, KS, nmg);
    }

    // vmean = (mean_L h)@wv^T + bv ; cw = vmean@wo^T + bo (exact fp32 identity)
    colmean1<<<dim3(B, CMC), 256, 0, stream>>>(h, partC, L);
    colmean2<<<B*DM/256, 256, 0, stream>>>(partC, hm, L);
    tiny_gemm<<<B, 256, 0, stream>>>(hm, wv_i, bv_i, vmean, DM, DM);
    tiny_gemm<<<B, 256, 0, stream>>>(vmean, wo_i, bo_i, cw, DM, DM);

    scatter_delta<<<B*8*u, 256, 0, stream>>>(ctxt_all, vmean, wo_i, top_all, h, L, u);

    unsigned short* ybuf = P0;
    unsigned short* mid  = P1;
    unsigned short* y2b  = P0 + (size_t)RF*DM;
    const float* l1g = ln1g + (size_t)layer*DM; const float* l1b = ln1b + (size_t)layer*DM;
    const float* l2g = ln2g + (size_t)layer*DM; const float* l2b = ln2b + (size_t)layer*DM;
    for (int r0 = 0; r0 < M; r0 += RF){
      ln_kernel<<<RF/4, 256, 0, stream>>>(h + (size_t)r0*DM, nullptr, 0, l1g, l1b, ybuf, 1, cw, L, r0);
      bgemm2<128,0><<<dim3(16, RF/128), 256, 0, stream>>>(ybuf, w1b, b1_i, mid,
          2048, 512, L, 0, 1, 1, 0, 0, 8);
      bgemm_dp<32><<<dim3(8, RF/128), 256, 0, stream>>>(mid, w2b, b2_i, y2b,
          512, 0, 1, 0, 0, 8);
      ln_kernel<<<RF/4, 256, 0, stream>>>(h + (size_t)r0*DM, y2b, 1, l2g, l2b, h + (size_t)r0*DM, 0, cw, L, r0);
    }

    if (layer < 2){
      const float* db = dcb + (size_t)layer*DM;
      unsigned short* convb = P0;
      bgemm2<128,1><<<dim3(4, M/128), 256, 0, stream>>>(h, wtapK, db, convb,
          512, 1536, L, 1, 0, 1, 0, 0, 16);
      bnstat1<<<dim3(8, 128), 256, 0, stream>>>(convb, partS, partQ, M/128);
      bnstat2<<<2, 256, 0, stream>>>(partS, partQ, stats, 128, M);
      int Lo = L/2;
      bnpool<<<(int)(((size_t)B*Lo*DM)/256), 256, 0, stream>>>(convb, stats,
          bng + (size_t)layer*DM, bnb + (size_t)layer*DM, h, hb, L, Lo);
      L = Lo;
    }
  }

  final_kernel<<<B, 128, 0, stream>>>(h, x, flg, flb, pw, pb, skw, skb, (float*)d_out, L, L0);
}

// Round 14
// 4680.823 us; speedup vs baseline: 1.0214x; 1.0001x over previous
//
#include <hip/hip_runtime.h>
#include <cmath>

#define DM 512
#define DH 64

typedef __attribute__((ext_vector_type(8))) short short8;
typedef __attribute__((ext_vector_type(4))) float float4v;

__device__ inline float b2f(unsigned short u){
  union{unsigned int i; float f;} z; z.i = ((unsigned)u)<<16; return z.f;
}
__device__ inline unsigned short f2b(float f){
  unsigned int x = __float_as_uint(f);
  return (unsigned short)((x + 0x7fffu + ((x>>16)&1u)) >> 16);   // RNE
}
// HW packed RNE convert: lo16 = bf16(a), hi16 = bf16(b)
__device__ inline unsigned cvtpk2(float a, float b){
  unsigned r; asm("v_cvt_pk_bf16_f32 %0, %1, %2" : "=v"(r) : "v"(a), "v"(b)); return r;
}

#define GLL(gp, lp) __builtin_amdgcn_global_load_lds((const __attribute__((address_space(1))) void*)(gp), \
    (__attribute__((address_space(3))) void*)(lp), 16, 0, 0)

// ---------------- Threefry-2x32-20 (matches jax.random) ----------------
__host__ __device__ inline void tf2x32(unsigned k0, unsigned k1, unsigned& x0, unsigned& x1){
  const unsigned ks0=k0, ks1=k1, ks2=k0^k1^0x1BD11BDAu;
  x0 += ks0; x1 += ks1;
#define TF_ROT(r) { x0 += x1; x1 = (x1<<(r))|(x1>>(32-(r))); x1 ^= x0; }
  TF_ROT(13) TF_ROT(15) TF_ROT(26) TF_ROT(6)
  x0 += ks1; x1 += ks2 + 1u;
  TF_ROT(17) TF_ROT(29) TF_ROT(16) TF_ROT(24)
  x0 += ks2; x1 += ks0 + 2u;
  TF_ROT(13) TF_ROT(15) TF_ROT(26) TF_ROT(6)
  x0 += ks0; x1 += ks1 + 3u;
  TF_ROT(17) TF_ROT(29) TF_ROT(16) TF_ROT(24)
  x0 += ks1; x1 += ks2 + 4u;
  TF_ROT(13) TF_ROT(15) TF_ROT(26) TF_ROT(6)
  x0 += ks2; x1 += ks0 + 5u;
#undef TF_ROT
}

__global__ __launch_bounds__(256) void idx_kernel(int* __restrict__ idx, unsigned k2a, unsigned k2b,
                                                  int S2, int Lmask){
  int j = blockIdx.x*256 + threadIdx.x;
  if (j >= S2) return;
  unsigned x0 = (unsigned)j, x1 = (unsigned)(S2 + j);
  tf2x32(k2a, k2b, x0, x1);
  idx[j]      = (int)(x0 & (unsigned)Lmask);
  idx[S2 + j] = (int)(x1 & (unsigned)Lmask);
}

// ---------------- positional-embedding table (batch-independent) ----------------
__global__ __launch_bounds__(256) void pe_kernel(float* __restrict__ pe, int L){
  int i = blockIdx.x*256 + threadIdx.x;
  int d = i % DM, l = i / DM;
  const float scale = -0.017988946f;  // -ln(10000)/512
  float freq = expf((float)(d & ~1) * scale);
  float ang  = (float)l * freq;
  pe[i] = (d & 1) ? cosf(ang) : sinf(ang);
}

// ---------------- transpose token-conv weights: tcwT[j][d] = tcw[d][c][kk], j=kk*7+c ----------------
__global__ __launch_bounds__(256) void packtcw(const float* __restrict__ tcw, float* __restrict__ tcwT){
  int i = blockIdx.x*256 + threadIdx.x;
  if (i >= 21*DM) return;
  int j = i / DM, d = i % DM;
  tcwT[(size_t)j*DM + d] = tcw[(size_t)d*21 + (j%7)*3 + (j/7)];
}

// ---------------- token embed: one block per (b,l) row; optional bf16 shadow hb ----------------
__global__ __launch_bounds__(256) void embed2(const float* __restrict__ x, const float* __restrict__ tcwT,
                                              const float* __restrict__ pe, float* __restrict__ h,
                                              unsigned short* __restrict__ hb, int L){
  int row = blockIdx.x; int l = row % L, b = row / L;
  __shared__ float xs[21];
  int t = threadIdx.x;
  if (t < 21){
    int c = t % 7, kk = t / 7;
    int ls = l + kk - 1; ls = (ls < 0) ? ls + L : (ls >= L ? ls - L : ls);
    xs[t] = x[((size_t)b*L + ls)*7 + c];
  }
  __syncthreads();
  for (int d = t; d < DM; d += 256){
    float acc = 0.f;
#pragma unroll
    for (int j=0;j<21;j++) acc += xs[j]*tcwT[j*DM + d];
    float val = acc + pe[(size_t)l*DM + d];
    h[(size_t)row*DM + d] = val;
    if (hb) hb[(size_t)row*DM + d] = f2b(val);
  }
}

// ---------------- fp32 -> bf16 conversion ----------------
__global__ __launch_bounds__(256) void f2b_vec(const float* __restrict__ src, unsigned short* __restrict__ dst, int n4){
  int i = blockIdx.x*256 + threadIdx.x;
  if (i >= n4) return;
  float4 v = ((const float4*)src)[i];
  uint2 o; o.x = cvtpk2(v.x, v.y); o.y = cvtpk2(v.z, v.w);
  ((uint2*)dst)[i] = o;
}

// ---------------- pack conv weights along K: wtapK[n][tap*512+c] = dcw[n][c][tap] ----------------
__global__ __launch_bounds__(256) void packconv(const float* __restrict__ dcw, unsigned short* __restrict__ wtapK){
  int i = blockIdx.x*256 + threadIdx.x;
  if (i >= 3*DM*DM) return;
  int n = i / (3*DM); int rem = i % (3*DM); int tap = rem / DM; int c = rem % DM;
  wtapK[(size_t)n*(3*DM) + tap*DM + c] = f2b(dcw[((size_t)n*DM + c)*3 + tap]);
}

// ---------------- concat qkv bias ----------------
__global__ __launch_bounds__(256) void catb_kernel(const float* __restrict__ a, const float* __restrict__ b,
    const float* __restrict__ c, float* __restrict__ o){
  int i = blockIdx.x*256 + threadIdx.x;
  if (i >= 1536) return;
  o[i] = (i < 512) ? a[i] : (i < 1024 ? b[i-512] : c[i-1024]);
}

// =======================================================================
// bgemm_dp: counted-vmcnt 3-deep pipelined GEMM (T3+T4), bf16 A, TN=64,
// K = NITER*64. LDS ring: 3 stages x (16KB A + 8KB B) = 72KB -> 2 blk/CU.
// Per iter: s_waitcnt vmcnt(12/6/0) -> barrier -> MFMA on slot t%3 ->
// barrier -> issue tile t+3 into slot t%3 (steady state never drains).
// Epilogue: conflict-free LDS-staged coalesced writeback.
// Used for QKV (bf16 shadow A) and w2 (bf16 mid A).
// =======================================================================
template<int NITER>
__global__ __launch_bounds__(256) void bgemm_dp(const unsigned short* __restrict__ A16,
    const unsigned short* __restrict__ Wb, const float* __restrict__ bias, void* __restrict__ C,
    int N, int act, int outbf, int qkv, size_t bufstride, int swz){
  constexpr int TN = 64, NJ = 2, SWM = TN/16 - 1;
  const int K = NITER*64;
  __shared__ unsigned short LDSB[3*12288];    // 3 x 24KB
  int tid = threadIdx.x;
  int w = tid >> 6, ln = tid & 63;

  int bx = blockIdx.x, by = blockIdx.y;
  if (swz){
    int XT = gridDim.x, YT = gridDim.y;
    int lid = by*XT + bx;
    int xcd = lid & 7, s = lid >> 3;
    int ych = YT >> 3;
    int CHv = ych < swz ? ych : swz;
    int yloc = s % CHv;
    int t2 = s / CHv;
    int xx = t2 % XT;
    int chunk = t2 / XT;
    by = xcd*ych + chunk*CHv + yloc;
    bx = xx;
  }
  int row0 = by*128, col0 = bx*TN;

  long aBase[4]; int aCol[4];
#pragma unroll
  for (int g=0; g<4; g++){
    int ch = g*256 + tid;
    int r = ch >> 3, c = ch & 7;
    aCol[g] = (c ^ (r & 7))*8;
    aBase[g] = (long)(row0 + r) * K;
  }
  long bBase[2];
#pragma unroll
  for (int g=0; g<2; g++){
    int ch = g*256 + tid;
    int r = ch >> 3, c = ch & 7;
    bBase[g] = (long)(col0 + r)*K + (c ^ (r & 7))*8;
  }
  int raBase[4], rbBase[2];
#pragma unroll
  for (int i=0;i<4;i++)  raBase[i] = ((w&1)*64 + i*16 + (ln&15))*8;
#pragma unroll
  for (int j=0;j<2;j++)  rbBase[j] = ((w>>1)*32 + j*16 + (ln&15))*8;

  float4v acc[4][NJ] = {};

  auto issue = [&](int t, int slot){
    int k0 = t*64;
    char* sa = (char*)LDSB + slot*24576;
    char* sb = sa + 16384;
#pragma unroll
    for (int g=0; g<4; g++)
      GLL(A16 + aBase[g] + k0 + aCol[g], sa + g*4096 + w*1024);
#pragma unroll
    for (int g=0; g<2; g++)
      GLL(Wb + bBase[g] + k0, sb + g*4096 + w*1024);
  };

  issue(0, 0);
  issue(1, 1);
  issue(2, 2);

  int slot = 0;
  for (int t=0; t<NITER; t++){
    if (t+2 < NITER)      asm volatile("s_waitcnt vmcnt(12)" ::: "memory");
    else if (t+1 < NITER) asm volatile("s_waitcnt vmcnt(6)" ::: "memory");
    else                  asm volatile("s_waitcnt vmcnt(0)" ::: "memory");
    __builtin_amdgcn_s_barrier();
    asm volatile("" ::: "memory");
    const char* ab = (const char*)LDSB + slot*24576;
    const char* bb = ab + 16384;
#pragma unroll
    for (int s=0;s<2;s++){
      int xs = (s*4 + (ln>>4)) ^ (ln&7);
      short8 af[4], bf[NJ];
#pragma unroll
      for (int i=0;i<4;i++)  af[i] = *(const short8*)(ab + (raBase[i] + xs)*16);
#pragma unroll
      for (int j=0;j<NJ;j++) bf[j] = *(const short8*)(bb + (rbBase[j] + xs)*16);
#pragma unroll
      for (int i=0;i<4;i++)
#pragma unroll
        for (int j=0;j<NJ;j++)
          acc[i][j] = __builtin_amdgcn_mfma_f32_16x16x32_bf16(af[i], bf[j], acc[i][j], 0, 0, 0);
    }
    __builtin_amdgcn_s_barrier();
    asm volatile("" ::: "memory");
    if (t+3 < NITER) issue(t+3, slot);
    slot = (slot==2) ? 0 : slot+1;
  }

  float* Cf = (float*)C;
  unsigned short* Cb = (unsigned short*)C;
  if (outbf){
    int clBase = (w>>1)*32 + (ln & 15);
#pragma unroll
    for (int i=0;i<4;i++){
      int rlBase = (w&1)*64 + i*16 + (ln>>4)*4;
      int xr = ((rlBase>>2) & SWM) << 4;
#pragma unroll
      for (int j=0;j<NJ;j++){
        int cl = clBase + j*16;
        int colb = col0 + cl;
        float vv[4];
#pragma unroll
        for (int r=0;r<4;r++){
          float v = acc[i][j][r];
          if (bias) v += bias[colb];
          if (act){
            float z = 0.7978845608f * v * (1.f + 0.044715f*v*v);
            float e = __expf(2.f*z);
            v = v * (1.f - 1.f/(e + 1.f));
          }
          vv[r] = v;
        }
        unsigned p01 = cvtpk2(vv[0], vv[1]);
        unsigned p23 = cvtpk2(vv[2], vv[3]);
        int sc = cl ^ xr;
        LDSB[(rlBase+0)*TN + sc] = (unsigned short)p01;
        LDSB[(rlBase+1)*TN + sc] = (unsigned short)(p01>>16);
        LDSB[(rlBase+2)*TN + sc] = (unsigned short)p23;
        LDSB[(rlBase+3)*TN + sc] = (unsigned short)(p23>>16);
      }
    }
    __syncthreads();
    constexpr int CPR = TN/8;
#pragma unroll
    for (int e = 0; e < 128*CPR; e += 256){
      int idx = e + tid;
      int rl = idx / CPR, c8 = (idx % CPR)*8;
      int sc8 = c8 ^ (((rl>>2) & SWM) << 4);
      uint4 val = *(const uint4*)&LDSB[rl*TN + sc8];
      int grow = row0 + rl;
      int colb = col0 + c8;
      if (qkv){
        int bsel = colb >> 9;
        *(uint4*)&Cb[(size_t)bsel*bufstride + (size_t)grow*512 + (colb & 511)] = val;
      } else {
        *(uint4*)&Cb[(size_t)grow*N + colb] = val;
      }
    }
  } else {
    int colb0 = col0 + (w>>1)*32 + (ln & 15);
#pragma unroll
    for (int i=0;i<4;i++){
      int growb = row0 + (w&1)*64 + i*16 + (ln>>4)*4;
#pragma unroll
      for (int j=0;j<NJ;j++){
        int colb = colb0 + j*16;
#pragma unroll
        for (int r=0;r<4;r++){
          float v = acc[i][j][r];
          if (bias) v += bias[colb];
          if (act){
            float z = 0.7978845608f * v * (1.f + 0.044715f*v*v);
            float e = __expf(2.f*z);
            v = v * (1.f - 1.f/(e + 1.f));
          }
          Cf[(size_t)(growb+r)*N + colb] = v;
        }
      }
    }
  }
}

// =======================================================================
// bgemm_dpc: bgemm_dp + circular conv addressing (K=1536 = 3 taps over a
// 512-wide bf16 A with per-row prev/next shifts). Reads the hb shadow
// (refreshed by ln2); same counted-vmcnt 3-deep ring, same epilogue.
// =======================================================================
template<int NITER>
__global__ __launch_bounds__(256) void bgemm_dpc(const unsigned short* __restrict__ A16,
    const unsigned short* __restrict__ Wb, const float* __restrict__ bias, void* __restrict__ C,
    int N, int L, int swz){
  constexpr int TN = 64, NJ = 2, SWM = TN/16 - 1;
  const int K = NITER*64;       // 1536: B row stride
  const int KA = 512;           // A row stride
  __shared__ unsigned short LDSB[3*12288];    // 3 x 24KB
  int tid = threadIdx.x;
  int w = tid >> 6, ln = tid & 63;

  int bx = blockIdx.x, by = blockIdx.y;
  if (swz){
    int XT = gridDim.x, YT = gridDim.y;
    int lid = by*XT + bx;
    int xcd = lid & 7, s = lid >> 3;
    int ych = YT >> 3;
    int CHv = ych < swz ? ych : swz;
    int yloc = s % CHv;
    int t2 = s / CHv;
    int xx = t2 % XT;
    int chunk = t2 / XT;
    by = xcd*ych + chunk*CHv + yloc;
    bx = xx;
  }
  int row0 = by*128, col0 = bx*TN;

  long aBase[4], dPrev[4], dNext[4]; int aCol[4];
#pragma unroll
  for (int g=0; g<4; g++){
    int ch = g*256 + tid;
    int r = ch >> 3, c = ch & 7;
    aCol[g] = (c ^ (r & 7))*8;
    int gr = row0 + r;
    aBase[g] = (long)gr * KA;
    int l = gr % L;
    dPrev[g] = (l==0)   ? (long)(L-1)*KA : -(long)KA;
    dNext[g] = (l==L-1) ? -(long)(L-1)*KA : (long)KA;
  }
  long bBase[2];
#pragma unroll
  for (int g=0; g<2; g++){
    int ch = g*256 + tid;
    int r = ch >> 3, c = ch & 7;
    bBase[g] = (long)(col0 + r)*K + (c ^ (r & 7))*8;
  }
  int raBase[4], rbBase[2];
#pragma unroll
  for (int i=0;i<4;i++)  raBase[i] = ((w&1)*64 + i*16 + (ln&15))*8;
#pragma unroll
  for (int j=0;j<2;j++)  rbBase[j] = ((w>>1)*32 + j*16 + (ln&15))*8;

  float4v acc[4][NJ] = {};

  auto issue = [&](int t, int slot){
    int k0 = t*64;
    int kk = k0 & 511;
    int seg = k0 >> 9;
    char* sa = (char*)LDSB + slot*24576;
    char* sb = sa + 16384;
#pragma unroll
    for (int g=0; g<4; g++){
      long d = (seg==0) ? dPrev[g] : (seg==2 ? dNext[g] : 0);
      GLL(A16 + aBase[g] + d + kk + aCol[g], sa + g*4096 + w*1024);
    }
#pragma unroll
    for (int g=0; g<2; g++)
      GLL(Wb + bBase[g] + k0, sb + g*4096 + w*1024);
  };

  issue(0, 0);
  issue(1, 1);
  issue(2, 2);

  int slot = 0;
  for (int t=0; t<NITER; t++){
    if (t+2 < NITER)      asm volatile("s_waitcnt vmcnt(12)" ::: "memory");
    else if (t+1 < NITER) asm volatile("s_waitcnt vmcnt(6)" ::: "memory");
    else                  asm volatile("s_waitcnt vmcnt(0)" ::: "memory");
    __builtin_amdgcn_s_barrier();
    asm volatile("" ::: "memory");
    const char* ab = (const char*)LDSB + slot*24576;
    const char* bb = ab + 16384;
#pragma unroll
    for (int s=0;s<2;s++){
      int xs = (s*4 + (ln>>4)) ^ (ln&7);
      short8 af[4], bf[NJ];
#pragma unroll
      for (int i=0;i<4;i++)  af[i] = *(const short8*)(ab + (raBase[i] + xs)*16);
#pragma unroll
      for (int j=0;j<NJ;j++) bf[j] = *(const short8*)(bb + (rbBase[j] + xs)*16);
#pragma unroll
      for (int i=0;i<4;i++)
#pragma unroll
        for (int j=0;j<NJ;j++)
          acc[i][j] = __builtin_amdgcn_mfma_f32_16x16x32_bf16(af[i], bf[j], acc[i][j], 0, 0, 0);
    }
    __builtin_amdgcn_s_barrier();
    asm volatile("" ::: "memory");
    if (t+3 < NITER) issue(t+3, slot);
    slot = (slot==2) ? 0 : slot+1;
  }

  unsigned short* Cb = (unsigned short*)C;
  int clBase = (w>>1)*32 + (ln & 15);
#pragma unroll
  for (int i=0;i<4;i++){
    int rlBase = (w&1)*64 + i*16 + (ln>>4)*4;
    int xr = ((rlBase>>2) & SWM) << 4;
#pragma unroll
    for (int j=0;j<NJ;j++){
      int cl = clBase + j*16;
      int colb = col0 + cl;
      float vv[4];
#pragma unroll
      for (int r=0;r<4;r++){
        float v = acc[i][j][r];
        if (bias) v += bias[colb];
        vv[r] = v;
      }
      unsigned p01 = cvtpk2(vv[0], vv[1]);
      unsigned p23 = cvtpk2(vv[2], vv[3]);
      int sc = cl ^ xr;
      LDSB[(rlBase+0)*TN + sc] = (unsigned short)p01;
      LDSB[(rlBase+1)*TN + sc] = (unsigned short)(p01>>16);
      LDSB[(rlBase+2)*TN + sc] = (unsigned short)p23;
      LDSB[(rlBase+3)*TN + sc] = (unsigned short)(p23>>16);
    }
  }
  __syncthreads();
  constexpr int CPR = TN/8;
#pragma unroll
  for (int e = 0; e < 128*CPR; e += 256){
    int idx = e + tid;
    int rl = idx / CPR, c8 = (idx % CPR)*8;
    int sc8 = c8 ^ (((rl>>2) & SWM) << 4);
    uint4 val = *(const uint4*)&LDSB[rl*TN + sc8];
    int grow = row0 + rl;
    int colb = col0 + c8;
    *(uint4*)&Cb[(size_t)grow*N + colb] = val;
  }
}

// =======================================================================
// bgemm2 (R9 form): bf16 MFMA GEMM, 128xTN tile, BK=64, single-buffered
// staging + conflict-free LDS-staged coalesced epilogue.
// Used for QKV fallback (A32), w1 (TN=128) and conv fallback (A32).
// =======================================================================
template<int TN, int A32>
__global__ __launch_bounds__(256) void bgemm2(const void* __restrict__ Ain,
    const unsigned short* __restrict__ Wb, const float* __restrict__ bias, void* __restrict__ C,
    int N, int K, int L, int convmode, int act, int outbf, int qkv, size_t bufstride, int swz){
  constexpr int NJ = TN/32;
  constexpr int BR = TN/32;
  constexpr int SWM = TN/16 - 1;
  __shared__ unsigned short LDSBUF[128*64 + TN*64];
  unsigned short* As = LDSBUF;
  unsigned short* Bs = LDSBUF + 128*64;
  int tid = threadIdx.x;
  int w = tid >> 6, ln = tid & 63;

  int bx = blockIdx.x, by = blockIdx.y;
  if (swz){
    int XT = gridDim.x, YT = gridDim.y;
    int lid = by*XT + bx;
    int xcd = lid & 7, s = lid >> 3;
    int ych = YT >> 3;
    int CHv = ych < swz ? ych : swz;
    int yloc = s % CHv;
    int t2 = s / CHv;
    int xx = t2 % XT;
    int chunk = t2 / XT;
    by = xcd*ych + chunk*CHv + yloc;
    bx = xx;
  }
  int row0 = by*128, col0 = bx*TN;
  int KA = convmode ? 512 : K;

  long aBase[4], dPrev[4], dNext[4]; int aCol[4];
#pragma unroll
  for (int g=0; g<4; g++){
    int ch = g*256 + tid;
    int r = ch >> 3, c = ch & 7;
    int gc = c ^ (r & 7);
    int gr = row0 + r;
    aCol[g] = gc*8;
    aBase[g] = (long)gr * KA;
    if (convmode){
      int l = gr % L;
      dPrev[g] = (l==0)   ? (long)(L-1)*KA : -(long)KA;
      dNext[g] = (l==L-1) ? -(long)(L-1)*KA : (long)KA;
    } else { dPrev[g]=0; dNext[g]=0; }
  }
  long bBase[BR];
#pragma unroll
  for (int g=0; g<BR; g++){
    int ch = g*256 + tid;
    int r = ch >> 3, c = ch & 7;
    int gc = c ^ (r & 7);
    bBase[g] = (long)(col0 + r)*K + gc*8;
  }
  int raBase[4], rbBase[NJ];
#pragma unroll
  for (int i=0;i<4;i++)  raBase[i] = ((w&1)*64 + i*16 + (ln&15))*8;
#pragma unroll
  for (int j=0;j<NJ;j++) rbBase[j] = ((w>>1)*(TN/2) + j*16 + (ln&15))*8;

  float4v acc[4][NJ] = {};
  int nIter = K/64;
  const unsigned short* A16 = (const unsigned short*)Ain;
  const float* Af = (const float*)Ain;

  for (int it=0; it<nIter; it++){
    int k0 = it*64;
    int kk = convmode ? (k0 & 511) : k0;
    int seg = convmode ? (k0 >> 9) : 1;
    if (A32){
#pragma unroll
      for (int g=0; g<4; g++){
        long d = convmode ? ((seg==0) ? dPrev[g] : (seg==2 ? dNext[g] : 0)) : 0;
        const float* src = Af + aBase[g] + d + kk + aCol[g];
        float4 v0 = *(const float4*)src;
        float4 v1 = *(const float4*)(src+4);
        uint4 pk;
        pk.x = cvtpk2(v0.x, v0.y); pk.y = cvtpk2(v0.z, v0.w);
        pk.z = cvtpk2(v1.x, v1.y); pk.w = cvtpk2(v1.z, v1.w);
        *(uint4*)((char*)As + g*4096 + tid*16) = pk;
      }
    } else {
#pragma unroll
      for (int g=0; g<4; g++){
        long d = convmode ? ((seg==0) ? dPrev[g] : (seg==2 ? dNext[g] : 0)) : 0;
        GLL(A16 + aBase[g] + d + kk + aCol[g], (char*)As + g*4096 + w*1024);
      }
    }
#pragma unroll
    for (int g=0; g<BR; g++)
      GLL(Wb + bBase[g] + k0, (char*)Bs + g*4096 + w*1024);
    __syncthreads();
    const char* ab = (const char*)As;
    const char* bb = (const char*)Bs;
#pragma unroll
    for (int s=0;s<2;s++){
      int xs = (s*4 + (ln>>4)) ^ (ln&7);
      short8 af[4], bf[NJ];
#pragma unroll
      for (int i=0;i<4;i++)  af[i] = *(const short8*)(ab + (raBase[i] + xs)*16);
#pragma unroll
      for (int j=0;j<NJ;j++) bf[j] = *(const short8*)(bb + (rbBase[j] + xs)*16);
#pragma unroll
      for (int i=0;i<4;i++)
#pragma unroll
        for (int j=0;j<NJ;j++)
          acc[i][j] = __builtin_amdgcn_mfma_f32_16x16x32_bf16(af[i], bf[j], acc[i][j], 0, 0, 0);
    }
    __syncthreads();
  }

  float* Cf = (float*)C;
  unsigned short* Cb = (unsigned short*)C;
  if (outbf){
    int clBase = (w>>1)*(TN/2) + (ln & 15);
#pragma unroll
    for (int i=0;i<4;i++){
      int rlBase = (w&1)*64 + i*16 + (ln>>4)*4;
      int xr = ((rlBase>>2) & SWM) << 4;
#pragma unroll
      for (int j=0;j<NJ;j++){
        int cl = clBase + j*16;
        int colb = col0 + cl;
        float vv[4];
#pragma unroll
        for (int r=0;r<4;r++){
          float v = acc[i][j][r];
          if (bias) v += bias[colb];
          if (act){
            float z = 0.7978845608f * v * (1.f + 0.044715f*v*v);
            float e = __expf(2.f*z);
            v = v * (1.f - 1.f/(e + 1.f));
          }
          vv[r] = v;
        }
        unsigned p01 = cvtpk2(vv[0], vv[1]);
        unsigned p23 = cvtpk2(vv[2], vv[3]);
        int sc = cl ^ xr;
        LDSBUF[(rlBase+0)*TN + sc] = (unsigned short)p01;
        LDSBUF[(rlBase+1)*TN + sc] = (unsigned short)(p01>>16);
        LDSBUF[(rlBase+2)*TN + sc] = (unsigned short)p23;
        LDSBUF[(rlBase+3)*TN + sc] = (unsigned short)(p23>>16);
      }
    }
    __syncthreads();
    constexpr int CPR = TN/8;
#pragma unroll
    for (int e = 0; e < 128*CPR; e += 256){
      int idx = e + tid;
      int rl = idx / CPR, c8 = (idx % CPR)*8;
      int sc8 = c8 ^ (((rl>>2) & SWM) << 4);
      uint4 val = *(const uint4*)&LDSBUF[rl*TN + sc8];
      int grow = row0 + rl;
      int colb = col0 + c8;
      if (qkv){
        int bsel = colb >> 9;
        *(uint4*)&Cb[(size_t)bsel*bufstride + (size_t)grow*512 + (colb & 511)] = val;
      } else {
        *(uint4*)&Cb[(size_t)grow*N + colb] = val;
      }
    }
  } else {
    int colb0 = col0 + (w>>1)*(TN/2) + (ln & 15);
#pragma unroll
    for (int i=0;i<4;i++){
      int growb = row0 + (w&1)*64 + i*16 + (ln>>4)*4;
#pragma unroll
      for (int j=0;j<NJ;j++){
        int colb = colb0 + j*16;
#pragma unroll
        for (int r=0;r<4;r++){
          float v = acc[i][j][r];
          if (bias) v += bias[colb];
          if (act){
            float z = 0.7978845608f * v * (1.f + 0.044715f*v*v);
            float e = __expf(2.f*z);
            v = v * (1.f - 1.f/(e + 1.f));
          }
          Cf[(size_t)(growb+r)*N + colb] = v;
        }
      }
    }
  }
}

// ---------------- sample_m2: one wave per (b,l), all 8 heads; 16B/lane loads ----------------
__global__ __launch_bounds__(256) void sample_m2(const unsigned short* __restrict__ q,
    const unsigned short* __restrict__ k, const int* __restrict__ idx, float* __restrict__ m, int L, int u){
  int w = (blockIdx.x*256 + threadIdx.x) >> 6;
  int lane = threadIdx.x & 63;
  int l = w % L; int b = w / L;
  const unsigned short* qrow = q + (size_t)w*DM + lane*8;
  uint4 qq = *(const uint4*)qrow;
  float qv[8];
  qv[0]=b2f((unsigned short)(qq.x&0xffff)); qv[1]=b2f((unsigned short)(qq.x>>16));
  qv[2]=b2f((unsigned short)(qq.y&0xffff)); qv[3]=b2f((unsigned short)(qq.y>>16));
  qv[4]=b2f((unsigned short)(qq.z&0xffff)); qv[5]=b2f((unsigned short)(qq.z>>16));
  qv[6]=b2f((unsigned short)(qq.w&0xffff)); qv[7]=b2f((unsigned short)(qq.w>>16));
  const unsigned short* kb = k + (size_t)b*L*DM + lane*8;
  const int* ip = idx + (size_t)l*u;
  float mx = -1e30f, sum = 0.f;
  for (int s=0; s<u; s++){
    int kp = ip[s];
    uint4 kk = *(const uint4*)(kb + (size_t)kp*DM);
    float p;
    p  = qv[0]*b2f((unsigned short)(kk.x&0xffff)) + qv[1]*b2f((unsigned short)(kk.x>>16));
    p += qv[2]*b2f((unsigned short)(kk.y&0xffff)) + qv[3]*b2f((unsigned short)(kk.y>>16));
    p += qv[4]*b2f((unsigned short)(kk.z&0xffff)) + qv[5]*b2f((unsigned short)(kk.z>>16));
    p += qv[6]*b2f((unsigned short)(kk.w&0xffff)) + qv[7]*b2f((unsigned short)(kk.w>>16));
    p += __shfl_xor(p, 1); p += __shfl_xor(p, 2); p += __shfl_xor(p, 4);
    mx = fmaxf(mx, p); sum += p;
  }
  if ((lane & 7) == 0){
    int hh = lane >> 3;
    m[((size_t)b*8 + hh)*L + l] = mx - sum/(float)u;
  }
}

// ---------------- iterative top-u argmax per (b,h): register-resident, wave-shuffle reduce ----------------
template<int NS>
__global__ __launch_bounds__(256) void topk_kernel(const float* __restrict__ m, int* __restrict__ top, int L, int u){
  int bh = blockIdx.x;
  const float* mm = m + (size_t)bh*L;
  int t = threadIdx.x;
  float v[NS];
#pragma unroll
  for (int s=0; s<NS; s++) v[s] = mm[s*256 + t];
  __shared__ float rv[4];
  __shared__ int   ri[4];
  for (int it=0; it<u; it++){
    float bv = -1e30f; int bi = 0x7fffffff;
#pragma unroll
    for (int s=0; s<NS; s++){
      float x = v[s]; int i = s*256 + t;
      if (x > bv || (x == bv && i < bi)) { bv = x; bi = i; }
    }
#pragma unroll
    for (int off=32; off; off>>=1){
      float ov = __shfl_xor(bv, off); int oi = __shfl_xor(bi, off);
      if (ov > bv || (ov == bv && oi < bi)) { bv = ov; bi = oi; }
    }
    if ((t & 63) == 0){ rv[t>>6] = bv; ri[t>>6] = bi; }
    __syncthreads();
    bv = rv[0]; bi = ri[0];
#pragma unroll
    for (int k2=1; k2<4; k2++){
      float ov = rv[k2]; int oi = ri[k2];
      if (ov > bv || (ov == bv && oi < bi)) { bv = ov; bi = oi; }
    }
    if (t == 0) top[bh*u + it] = bi;
    if ((bi & 255) == t){
      int slot = bi >> 8;
#pragma unroll
      for (int s=0; s<NS; s++) if (s == slot) v[s] = -1e31f;
    }
    __syncthreads();
  }
}

// ---------------- column mean, two-stage ----------------
#define CMC 32
__global__ __launch_bounds__(256) void colmean1(const float* __restrict__ src, float* __restrict__ part, int L){
  int b = blockIdx.x, ch = blockIdx.y;
  int rpb = L / CMC;
  int t = threadIdx.x;
  const float* p = src + ((size_t)b*L + (size_t)ch*rpb)*DM;
  float s0 = 0.f, s1 = 0.f;
  for (int r=0; r<rpb; r++){ s0 += p[(size_t)r*DM + t]; s1 += p[(size_t)r*DM + t + 256]; }
  float* o = part + ((size_t)b*CMC + ch)*DM;
  o[t] = s0; o[t+256] = s1;
}
__global__ __launch_bounds__(256) void colmean2(const float* __restrict__ part, float* __restrict__ dst, int L){
  int i = blockIdx.x*256 + threadIdx.x;
  int d = i % DM, b = i / DM;
  float s = 0.f;
  for (int c=0; c<CMC; c++) s += part[((size_t)b*CMC + c)*DM + d];
  dst[i] = s / (float)L;
}

// ---------------- tiny fp32 GEMM: one block per row ----------------
__global__ __launch_bounds__(256) void tiny_gemm(const float* __restrict__ A, const float* __restrict__ W,
    const float* __restrict__ bias, float* __restrict__ C, int N, int K){
  int row = blockIdx.x;
  const float* ar = A + (size_t)row*K;
  __shared__ float as[DM];
  for (int k=threadIdx.x; k<K; k+=256) as[k] = ar[k];
  __syncthreads();
  for (int n = threadIdx.x; n < N; n += 256){
    float acc = bias ? bias[n] : 0.f;
    const float* wr = W + (size_t)n*K;
    for (int k=0; k<K; k++) acc += as[k]*wr[k];
    C[(size_t)row*N + n] = acc;
  }
}

// ---------------- gather q rows for top queries (bf16 q -> fp32 qred) ----------------
__global__ __launch_bounds__(256) void qred_kernel(const unsigned short* __restrict__ q, const int* __restrict__ top,
    float* __restrict__ qred, int L, int u, int n){
  int i = blockIdx.x*256 + threadIdx.x;
  if (i >= n) return;
  int d = i & 63; int rest = i >> 6; int j = rest % u; int bh = rest / u;
  int hh = bh & 7; int b = bh >> 3;
  int pos = top[bh*u + j];
  qred[i] = b2f(q[((size_t)b*L + pos)*DM + hh*DH + d]);
}

// =======================================================================
// flash_attn: fused QK^T -> online softmax -> PV, key-split partials.
// =======================================================================
#define FKT 128
__global__ __launch_bounds__(256) void flash_attn(const float* __restrict__ qred,
    const unsigned short* __restrict__ kbuf, const unsigned short* __restrict__ vbuf,
    float* __restrict__ partM, float* __restrict__ partL, float* __restrict__ partA,
    int L, int u, int KS){
  int ks = blockIdx.x, bh = blockIdx.y; int b = bh >> 3, h = bh & 7;
  int t = threadIdx.x;
  __shared__ float Qs[38*64];              // 9.7 KB
  __shared__ unsigned short Ks[FKT*64];    // 16 KB (xor-swizzled chunks)
  __shared__ unsigned short Vs[FKT*64];    // 16 KB (natural)
  __shared__ float Ss[38*FKT];             // 19.4 KB
  for (int i=t;i<u*64;i+=256) Qs[i] = qred[(size_t)bh*u*64 + i];
  int lane = t & 63, w = t >> 6;
  float rm[10], rl[10], racc[10];
#pragma unroll
  for (int j=0;j<10;j++){ rm[j]=-1e30f; rl[j]=0.f; racc[j]=0.f; }
  int nk = L / KS;
  int kbase = ks*nk;
  int key = t & 127, rh = t >> 7;
  for (int kt = 0; kt < nk; kt += FKT){
    __syncthreads();
    for (int e = t; e < FKT*8; e += 256){   // chunk id: k=e>>3, c=e&7 (16B chunks)
      int k = e >> 3, c = e & 7;
      size_t gidx = ((size_t)(b*L + kbase + kt + k))*DM + h*DH + c*8;
      *(uint4*)((char*)Ks + (size_t)(k*8 + (c ^ (k&7)))*16) = *(const uint4*)(kbuf + gidx);
      *(uint4*)((char*)Vs + (size_t)e*16) = *(const uint4*)(vbuf + gidx);
    }
    __syncthreads();
    // scores: thread (key, rh) computes rows rh, rh+2, ...
    for (int r = rh; r < u; r += 2){
      const float4* q4 = (const float4*)(Qs + r*64);
      float acc = 0.f;
#pragma unroll
      for (int c=0;c<8;c++){
        short8 kk = *(const short8*)((char*)Ks + (size_t)(key*8 + (c ^ (key&7)))*16);
        float4 qa = q4[c*2], qb = q4[c*2+1];
        acc += qa.x*b2f((unsigned short)kk[0]) + qa.y*b2f((unsigned short)kk[1])
             + qa.z*b2f((unsigned short)kk[2]) + qa.w*b2f((unsigned short)kk[3]);
        acc += qb.x*b2f((unsigned short)kk[4]) + qb.y*b2f((unsigned short)kk[5])
             + qb.z*b2f((unsigned short)kk[6]) + qb.w*b2f((unsigned short)kk[7]);
      }
      Ss[r*FKT + key] = acc * 0.125f;
    }
    __syncthreads();
    // online softmax + PV: wave w owns rows w, w+4, ... (lane = output dim)
    int j = 0;
    for (int r = w; r < u; r += 4, j++){
      float s0 = Ss[r*FKT + lane], s1 = Ss[r*FKT + 64 + lane];
      float mx = fmaxf(s0, s1);
#pragma unroll
      for (int off=32; off; off>>=1) mx = fmaxf(mx, __shfl_xor(mx, off));
      float newm = fmaxf(rm[j], mx);
      float scale = expf(rm[j] - newm);
      float p0 = expf(s0 - newm), p1 = expf(s1 - newm);
      float ps = p0 + p1;
#pragma unroll
      for (int off=32; off; off>>=1) ps += __shfl_xor(ps, off);
      rl[j] = rl[j]*scale + ps;
      rm[j] = newm;
      Ss[r*FKT + lane] = p0; Ss[r*FKT + 64 + lane] = p1;
      float a = racc[j]*scale;
      for (int k=0;k<FKT;k+=4){
        float pa = Ss[r*FKT+k], pb = Ss[r*FKT+k+1], pc = Ss[r*FKT+k+2], pd = Ss[r*FKT+k+3];
        a += pa*b2f(Vs[(k+0)*64+lane]) + pb*b2f(Vs[(k+1)*64+lane])
           + pc*b2f(Vs[(k+2)*64+lane]) + pd*b2f(Vs[(k+3)*64+lane]);
      }
      racc[j] = a;
    }
  }
  int j = 0;
  for (int r = w; r < u; r += 4, j++){
    size_t base = ((size_t)bh*KS + ks)*u + r;
    if (lane == 0){ partM[base] = rm[j]; partL[base] = rl[j]; }
    partA[base*64 + lane] = racc[j];
  }
}

// ---------------- merge key-split partials -> ctxt ----------------
__global__ __launch_bounds__(256) void flash_merge(const float* __restrict__ partM, const float* __restrict__ partL,
    const float* __restrict__ partA, float* __restrict__ ctxt, int u, int KS, int n){
  int i = blockIdx.x*256 + threadIdx.x;
  if (i >= n) return;
  int nn = i & 63; int rest = i >> 6; int r = rest % u; int bhl = rest / u;
  size_t base0 = ((size_t)bhl*KS)*u + r;
  float gm = -1e30f;
  for (int s=0;s<KS;s++) gm = fmaxf(gm, partM[base0 + (size_t)s*u]);
  float lt = 0.f, at = 0.f;
  for (int s=0;s<KS;s++){
    float e = expf(partM[base0 + (size_t)s*u] - gm);
    lt += partL[base0 + (size_t)s*u]*e;
    at += partA[(base0 + (size_t)s*u)*64 + nn]*e;
  }
  ctxt[i] = at / lt;
}

// ---------------- sparse correction: h[b,pos] += (ctxt - vmean_slice)@wo_slice^T ----------------
__global__ __launch_bounds__(256) void scatter_delta(const float* __restrict__ ctxt, const float* __restrict__ vmean,
    const float* __restrict__ wo, const int* __restrict__ top, float* __restrict__ h, int L, int u){
  int bid = blockIdx.x;
  int j = bid % u; int bh = bid / u; int hh = bh & 7; int b = bh >> 3;
  int pos = top[bh*u + j];
  __shared__ float delta[DH];
  int t = threadIdx.x;
  if (t < DH) delta[t] = ctxt[(size_t)(bh*u + j)*DH + t] - vmean[b*DM + hh*DH + t];
  __syncthreads();
  float* hrow = h + ((size_t)b*L + pos)*DM;
  const float* wbase = wo + hh*DH;
  for (int n = t; n < DM; n += 256){
    float acc = 0.f;
    const float* wr = wbase + (size_t)n*DM;
#pragma unroll
    for (int dd=0; dd<DH; dd++) acc += delta[dd] * wr[dd];
    atomicAdd(&hrow[n], acc);
  }
}

// ---------------- LayerNorm D=512, wave-per-row; optional bf16 shadow out ----------------
__global__ __launch_bounds__(256) void ln_kernel(const float* __restrict__ X, const void* __restrict__ Yadd,
    int yb, const float* __restrict__ g, const float* __restrict__ bta, void* __restrict__ Out, int ob,
    const float* __restrict__ cwv, int Lrow, int row0g, unsigned short* __restrict__ hbo){
  int w = threadIdx.x >> 6, lane = threadIdx.x & 63;
  size_t row = (size_t)blockIdx.x*4 + w;
  int d0 = lane*8;
  const float* xr = X + row*DM + d0;
  float4 a = *(const float4*)xr;
  float4 b = *(const float4*)(xr+4);
  float v[8] = {a.x,a.y,a.z,a.w,b.x,b.y,b.z,b.w};
  if (cwv){
    int bb = (int)(((size_t)row0g + row) / (size_t)Lrow);
    const float* cp = cwv + (size_t)bb*DM + d0;
    float4 c0 = *(const float4*)cp, c1 = *(const float4*)(cp+4);
    v[0]+=c0.x; v[1]+=c0.y; v[2]+=c0.z; v[3]+=c0.w;
    v[4]+=c1.x; v[5]+=c1.y; v[6]+=c1.z; v[7]+=c1.w;
  }
  if (Yadd){
    if (yb){
      const unsigned short* yr = (const unsigned short*)Yadd + row*DM + d0;
      uint4 yv = *(const uint4*)yr;
      v[0]+=b2f((unsigned short)(yv.x&0xffff)); v[1]+=b2f((unsigned short)(yv.x>>16));
      v[2]+=b2f((unsigned short)(yv.y&0xffff)); v[3]+=b2f((unsigned short)(yv.y>>16));
      v[4]+=b2f((unsigned short)(yv.z&0xffff)); v[5]+=b2f((unsigned short)(yv.z>>16));
      v[6]+=b2f((unsigned short)(yv.w&0xffff)); v[7]+=b2f((unsigned short)(yv.w>>16));
    } else {
      const float* yr = (const float*)Yadd + row*DM + d0;
      float4 y0 = *(const float4*)yr, y1 = *(const float4*)(yr+4);
      v[0]+=y0.x; v[1]+=y0.y; v[2]+=y0.z; v[3]+=y0.w;
      v[4]+=y1.x; v[5]+=y1.y; v[6]+=y1.z; v[7]+=y1.w;
    }
  }
  float s = 0.f, q = 0.f;
#pragma unroll
  for (int i=0;i<8;i++){ s += v[i]; q += v[i]*v[i]; }
#pragma unroll
  for (int off=32; off; off>>=1){ s += __shfl_xor(s,off); q += __shfl_xor(q,off); }
  float mu  = s * (1.0f/DM);
  float var = q * (1.0f/DM) - mu*mu;
  float r = rsqrtf(var + 1e-5f);
  const float* gp = g + d0; const float* bp = bta + d0;
  float4 g0 = *(const float4*)gp, g1 = *(const float4*)(gp+4);
  float4 b0 = *(const float4*)bp, b1 = *(const float4*)(bp+4);
  float gg[8] = {g0.x,g0.y,g0.z,g0.w,g1.x,g1.y,g1.z,g1.w};
  float bb2[8] = {b0.x,b0.y,b0.z,b0.w,b1.x,b1.y,b1.z,b1.w};
  float o[8];
#pragma unroll
  for (int i=0;i<8;i++) o[i] = (v[i]-mu)*r*gg[i] + bb2[i];
  if (ob){
    uint4 pk;
    pk.x = cvtpk2(o[0],o[1]); pk.y = cvtpk2(o[2],o[3]);
    pk.z = cvtpk2(o[4],o[5]); pk.w = cvtpk2(o[6],o[7]);
    *(uint4*)((unsigned short*)Out + row*DM + d0) = pk;
  } else {
    float* Of = (float*)Out + row*DM + d0;
    *(float4*)Of     = make_float4(o[0],o[1],o[2],o[3]);
    *(float4*)(Of+4) = make_float4(o[4],o[5],o[6],o[7]);
    if (hbo){
      uint4 pk;
      pk.x = cvtpk2(o[0],o[1]); pk.y = cvtpk2(o[2],o[3]);
      pk.z = cvtpk2(o[4],o[5]); pk.w = cvtpk2(o[6],o[7]);
      *(uint4*)&hbo[row*DM + d0] = pk;
    }
  }
}

// ---------------- BN partial sums over bf16 conv output (grid: 8 x 128) ----------------
__global__ __launch_bounds__(256) void bnstat1(const unsigned short* __restrict__ C, float* __restrict__ partS,
                                               float* __restrict__ partQ, int rpb){
  int chb = blockIdx.x;
  int mb  = blockIdx.y;
  int g = threadIdx.x >> 6, c = threadIdx.x & 63;
  int ch = chb*64 + c;
  float s = 0.f, q = 0.f;
  int r0 = mb * rpb;
  for (int r = r0 + g; r < r0 + rpb; r += 4){
    float v = b2f(C[(size_t)r*DM + ch]); s += v; q += v*v;
  }
  __shared__ float ls[4][64], lq[4][64];
  ls[g][c] = s; lq[g][c] = q;
  __syncthreads();
  if (g == 0){
    s = ls[0][c]+ls[1][c]+ls[2][c]+ls[3][c];
    q = lq[0][c]+lq[1][c]+lq[2][c]+lq[3][c];
    partS[(size_t)mb*DM + ch] = s;
    partQ[(size_t)mb*DM + ch] = q;
  }
}
__global__ __launch_bounds__(256) void bnstat2(const float* __restrict__ partS, const float* __restrict__ partQ,
                                               float* __restrict__ stats, int NB, int M){
  int ch = blockIdx.x*256 + threadIdx.x;
  if (ch >= DM) return;
  float s = 0.f, q = 0.f;
  for (int mb=0; mb<NB; mb++){
    s += partS[(size_t)mb*DM + ch];
    q += partQ[(size_t)mb*DM + ch];
  }
  float mu = s / (float)M;
  stats[ch] = mu;
  stats[DM + ch] = q / (float)M - mu*mu;
}

// ---------------- BN + ELU + maxpool(3,2); optional bf16 shadow hb ----------------
__global__ __launch_bounds__(256) void bnpool(const unsigned short* __restrict__ C, const float* __restrict__ stats,
    const float* __restrict__ g, const float* __restrict__ bta, float* __restrict__ Out,
    unsigned short* __restrict__ hb, int L, int Lo){
  size_t i = (size_t)blockIdx.x*256 + threadIdx.x;
  int ch = (int)(i % DM);
  size_t r = i / DM;
  int lo = (int)(r % Lo);
  int b  = (int)(r / Lo);
  float mu = stats[ch];
  float rstd = rsqrtf(stats[DM+ch] + 1e-5f);
  float gg = g[ch], bb = bta[ch];
  float best = -1e30f;
#pragma unroll
  for (int t=-1; t<=1; t++){
    int li = 2*lo + t;
    if (li >= 0 && li < L){
      float v = (b2f(C[((size_t)b*L + li)*DM + ch]) - mu)*rstd*gg + bb;
      v = v > 0.f ? v : expm1f(v);
      best = fmaxf(best, v);
    }
  }
  size_t oidx = ((size_t)b*Lo + lo)*DM + ch;
  Out[oidx] = best;
  if (hb) hb[oidx] = f2b(best);
}

// ---------------- final: LN(last row) @ proj^T + proj_b + skip ----------------
__global__ __launch_bounds__(128) void final_kernel(const float* __restrict__ h, const float* __restrict__ x,
    const float* __restrict__ fg, const float* __restrict__ fb, const float* __restrict__ pw,
    const float* __restrict__ pb, const float* __restrict__ sw, const float* __restrict__ sb,
    float* __restrict__ out, int Lf, int L0){
  int b = blockIdx.x;
  const float* row = h + ((size_t)b*Lf + (Lf-1))*DM;
  __shared__ float xn[DM];
  __shared__ float rs[2], rq[2];
  int t = threadIdx.x;
  float v[4]; float s = 0.f, q = 0.f;
#pragma unroll
  for (int i=0;i<4;i++){ v[i] = row[t + i*128]; s += v[i]; q += v[i]*v[i]; }
#pragma unroll
  for (int off=32; off; off>>=1){ s += __shfl_xor(s,off); q += __shfl_xor(q,off); }
  if ((t & 63) == 0){ rs[t>>6] = s; rq[t>>6] = q; }
  __syncthreads();
  s = rs[0]+rs[1]; q = rq[0]+rq[1];
  float mu = s*(1.0f/DM), var = q*(1.0f/DM) - mu*mu;
  float r = rsqrtf(var + 1e-5f);
#pragma unroll
  for (int i=0;i<4;i++){ int d = t + i*128; xn[d] = (v[i]-mu)*r*fg[d] + fb[d]; }
  __syncthreads();
  if (t < 96){
    float acc = pb[t] + sb[t];
    const float* xr = x + ((size_t)b*L0 + (L0-1))*7;
#pragma unroll
    for (int c=0;c<7;c++) acc += xr[c]*sw[t*7+c];
    for (int d=0; d<DM; d++) acc += xn[d]*pw[(size_t)t*DM + d];
    out[b*96 + t] = acc;
  }
}

// =======================================================================
extern "C" void kernel_launch(void* const* d_in, const int* in_sizes, int n_in,
                              void* d_out, int out_size, void* d_ws, size_t ws_size,
                              hipStream_t stream){
  const float* x    = (const float*)d_in[0];
  const float* skw  = (const float*)d_in[1];
  const float* skb  = (const float*)d_in[2];
  const float* tcw  = (const float*)d_in[3];
  const float* wq   = (const float*)d_in[4];
  const float* bq   = (const float*)d_in[5];
  const float* wk   = (const float*)d_in[6];
  const float* bk   = (const float*)d_in[7];
  const float* wv   = (const float*)d_in[8];
  const float* bv   = (const float*)d_in[9];
  const float* wo   = (const float*)d_in[10];
  const float* bo   = (const float*)d_in[11];
  const float* w1   = (const float*)d_in[12];
  const float* b1   = (const float*)d_in[13];
  const float* w2   = (const float*)d_in[14];
  const float* b2   = (const float*)d_in[15];
  const float* ln1g = (const float*)d_in[16];
  const float* ln1b = (const float*)d_in[17];
  const float* ln2g = (const float*)d_in[18];
  const float* ln2b = (const float*)d_in[19];
  const float* dcw  = (const float*)d_in[20];
  const float* dcb  = (const float*)d_in[21];
  const float* bng  = (const float*)d_in[22];
  const float* bnb  = (const float*)d_in[23];
  const float* flg  = (const float*)d_in[24];
  const float* flb  = (const float*)d_in[25];
  const float* pw   = (const float*)d_in[26];
  const float* pb   = (const float*)d_in[27];

  const int B = 32, L0 = 2048, DFF = 2048;
  const int RG = 16384;
  const int RF = 8192;
  char* ws = (char*)d_ws;
  const size_t SZH  = (size_t)B*L0*DM*sizeof(float);
  const size_t SLOT = (size_t)RG*DM*sizeof(unsigned short);

  const size_t WBSZ = (size_t)(3*DM*DM + 2*DFF*DM + 3*DM*DM)*2;
  size_t small_bytes = (size_t)L0*40*4
                     + (size_t)RG*8*4
                     + (size_t)B*8*40*4
                     + (size_t)32*8*40*64*4
                     + (size_t)32*8*40*64*4
                     + 3*(size_t)B*DM*4
                     + 2*(size_t)128*DM*4
                     + (size_t)2*DM*4
                     + (size_t)1536*4
                     + (size_t)B*CMC*DM*4
                     + (size_t)L0*DM*4
                     + (size_t)21*DM*4;
  size_t base_bytes = SZH + 4*SLOT + WBSZ + small_bytes;
  if (ws_size < base_bytes) return;
  // optional bf16 shadow of h (64 MB): pipelined QKV + pipelined conv
  size_t hb_off = (base_bytes + 255) & ~(size_t)255;
  size_t HBSZ = (size_t)B*L0*DM*2;
  int has_hb = (ws_size >= hb_off + HBSZ) ? 1 : 0;
  unsigned short* hb = has_hb ? (unsigned short*)(ws + hb_off) : nullptr;

  float*          h   = (float*)(ws);
  unsigned short* P0  = (unsigned short*)(ws + SZH);
  unsigned short* P1  = (unsigned short*)(ws + SZH + SLOT);
  unsigned short* P2  = (unsigned short*)(ws + SZH + 2*SLOT);
  unsigned short* P3  = (unsigned short*)(ws + SZH + 3*SLOT);
  unsigned short* wb  = (unsigned short*)(ws + SZH + 4*SLOT);
  unsigned short* wqb = wb;
  unsigned short* w1b = wqb + (size_t)3*DM*DM;
  unsigned short* w2b = w1b + (size_t)DFF*DM;
  unsigned short* wtapK= w2b + (size_t)DM*DFF;
  char* sm = ws + SZH + 4*SLOT + WBSZ;
  int*   idx_buf  = (int*)sm;
  float* m_buf    = (float*)(sm + (size_t)L0*40*4);
  int*   top_all  = (int*)((char*)m_buf + (size_t)RG*8*4);
  float* qred_loc = (float*)((char*)top_all + (size_t)B*8*40*4);
  float* ctxt_all = qred_loc + (size_t)32*8*40*64;
  float* hm       = ctxt_all + (size_t)32*8*40*64;
  float* vmean    = hm + (size_t)B*DM;
  float* cw       = vmean + (size_t)B*DM;
  float* partS    = cw + (size_t)B*DM;
  float* partQ    = partS + (size_t)128*DM;
  float* stats    = partQ + (size_t)128*DM;
  float* bqkv     = stats + (size_t)2*DM;
  float* partC    = bqkv + (size_t)1536;
  float* pe_buf   = partC + (size_t)B*CMC*DM;
  float* tcwT     = pe_buf + (size_t)L0*DM;

  // flash partials live in P0 (free during attention)
  float* fpM = (float*)P0;                       // 256*40
  float* fpL = fpM + (size_t)256*40;             // 256*40
  float* fpA = fpL + (size_t)256*40;             // 256*40*64 (~2.6 MB)

  auto conv_b = [&](const float* src, unsigned short* dst, size_t n){
    f2b_vec<<<(int)((n/4 + 255)/256), 256, 0, stream>>>(src, dst, (int)(n/4));
  };

  pe_kernel<<<(int)(((size_t)L0*DM)/256), 256, 0, stream>>>(pe_buf, L0);
  packtcw<<<(21*DM + 255)/256, 256, 0, stream>>>(tcw, tcwT);
  embed2<<<B*L0, 256, 0, stream>>>(x, tcwT, pe_buf, h, hb, L0);

  int L = L0;
  for (int layer = 0; layer < 3; layer++){
    int M = B * L;
    int u = (int)(5.0 * log((double)L + 1.0));   // 38 / 34 / 31
    int G = RG / L;
    int nG = M / RG;
    int KS = L / 512;                            // 4 / 2 / 1 key-splits
    const float* wv_i = wv + (size_t)layer*DM*DM;  const float* bv_i = bv + (size_t)layer*DM;
    const float* wo_i = wo + (size_t)layer*DM*DM;  const float* bo_i = bo + (size_t)layer*DM;
    const float* b1_i = b1 + (size_t)layer*DFF;
    const float* b2_i = b2 + (size_t)layer*DM;

    conv_b(wq + (size_t)layer*DM*DM, wqb,                    (size_t)DM*DM);
    conv_b(wk + (size_t)layer*DM*DM, wqb + (size_t)DM*DM,    (size_t)DM*DM);
    conv_b(wv_i,                     wqb + (size_t)2*DM*DM,  (size_t)DM*DM);
    conv_b(w1 + (size_t)layer*DFF*DM, w1b, (size_t)DFF*DM);
    conv_b(w2 + (size_t)layer*DM*DFF, w2b, (size_t)DM*DFF);
    catb_kernel<<<6, 256, 0, stream>>>(bq + (size_t)layer*DM, bk + (size_t)layer*DM, bv_i, bqkv);
    if (layer < 2)
      packconv<<<(3*DM*DM + 255)/256, 256, 0, stream>>>(dcw + (size_t)layer*DM*DM*3, wtapK);

    unsigned ka = 0u, kb2 = (unsigned)layer;
    tf2x32(0u, 42u, ka, kb2);
    unsigned a0 = 0u, a1 = 2u;  tf2x32(ka, kb2, a0, a1);
    unsigned c0 = 1u, c1 = 3u;  tf2x32(ka, kb2, c0, c1);
    int S2 = L * u / 2;
    idx_kernel<<<(S2 + 255)/256, 256, 0, stream>>>(idx_buf, a1, c1, S2, L-1);

    for (int g = 0; g < nG; g++){
      const float* hg = h + (size_t)g*RG*DM;
      if (has_hb){
        bgemm_dp<8><<<dim3(24, RG/128), 256, 0, stream>>>(hb + (size_t)g*RG*DM, wqb, bqkv, P1,
            1536, 0, 1, 1, (size_t)RG*DM, 16);
      } else {
        bgemm2<128,1><<<dim3(12, RG/128), 256, 0, stream>>>(hg, wqb, bqkv, P1,
            1536, 512, L, 0, 0, 1, 1, (size_t)RG*DM, 16);
      }
      sample_m2<<<RG/4, 256, 0, stream>>>(P1, P2, idx_buf, m_buf, L, u);
      int* top_g = top_all + (size_t)g*G*8*u;
      if (L == 2048)      topk_kernel<8><<<G*8, 256, 0, stream>>>(m_buf, top_g, L, u);
      else if (L == 1024) topk_kernel<4><<<G*8, 256, 0, stream>>>(m_buf, top_g, L, u);
      else                topk_kernel<2><<<G*8, 256, 0, stream>>>(m_buf, top_g, L, u);
      int nqr = G*8*u*DH;
      qred_kernel<<<(nqr + 255)/256, 256, 0, stream>>>(P1, top_g, qred_loc, L, u, nqr);

      flash_attn<<<dim3(KS, G*8), 256, 0, stream>>>(qred_loc, P2, P3, fpM, fpL, fpA, L, u, KS);
      int nmg = G*8*u*64;
      flash_merge<<<(nmg + 255)/256, 256, 0, stream>>>(fpM, fpL, fpA,
          ctxt_all + (size_t)g*G*8*u*64, u, KS, nmg);
    }

    // vmean = (mean_L h)@wv^T + bv ; cw = vmean@wo^T + bo (exact fp32 identity)
    colmean1<<<dim3(B, CMC), 256, 0, stream>>>(h, partC, L);
    colmean2<<<B*DM/256, 256, 0, stream>>>(partC, hm, L);
    tiny_gemm<<<B, 256, 0, stream>>>(hm, wv_i, bv_i, vmean, DM, DM);
    tiny_gemm<<<B, 256, 0, stream>>>(vmean, wo_i, bo_i, cw, DM, DM);

    scatter_delta<<<B*8*u, 256, 0, stream>>>(ctxt_all, vmean, wo_i, top_all, h, L, u);

    unsigned short* ybuf = P0;
    unsigned short* mid  = P1;
    unsigned short* y2b  = P0 + (size_t)RF*DM;
    const float* l1g = ln1g + (size_t)layer*DM; const float* l1b = ln1b + (size_t)layer*DM;
    const float* l2g = ln2g + (size_t)layer*DM; const float* l2b = ln2b + (size_t)layer*DM;
    int needc = (layer < 2) && has_hb;
    for (int r0 = 0; r0 < M; r0 += RF){
      ln_kernel<<<RF/4, 256, 0, stream>>>(h + (size_t)r0*DM, nullptr, 0, l1g, l1b, ybuf, 1, cw, L, r0, nullptr);
      bgemm2<128,0><<<dim3(16, RF/128), 256, 0, stream>>>(ybuf, w1b, b1_i, mid,
          2048, 512, L, 0, 1, 1, 0, 0, 8);
      bgemm_dp<32><<<dim3(8, RF/128), 256, 0, stream>>>(mid, w2b, b2_i, y2b,
          512, 0, 1, 0, 0, 8);
      ln_kernel<<<RF/4, 256, 0, stream>>>(h + (size_t)r0*DM, y2b, 1, l2g, l2b, h + (size_t)r0*DM, 0, cw, L, r0,
          needc ? (hb + (size_t)r0*DM) : nullptr);
    }

    if (layer < 2){
      const float* db = dcb + (size_t)layer*DM;
      unsigned short* convb = P0;
      if (has_hb){
        bgemm_dpc<24><<<dim3(8, M/128), 256, 0, stream>>>(hb, wtapK, db, convb,
            512, L, 16);
      } else {
        bgemm2<128,1><<<dim3(4, M/128), 256, 0, stream>>>(h, wtapK, db, convb,
            512, 1536, L, 1, 0, 1, 0, 0, 16);
      }
      bnstat1<<<dim3(8, 128), 256, 0, stream>>>(convb, partS, partQ, M/128);
      bnstat2<<<2, 256, 0, stream>>>(partS, partQ, stats, 128, M);
      int Lo = L/2;
      bnpool<<<(int)(((size_t)B*Lo*DM)/256), 256, 0, stream>>>(convb, stats,
          bng + (size_t)layer*DM, bnb + (size_t)layer*DM, h, hb, L, Lo);
      L = Lo;
    }
  }

  final_kernel<<<B, 128, 0, stream>>>(h, x, flg, flb, pw, pb, skw, skb, (float*)d_out, L, L0);
}